// Round 4
// baseline (469.909 us; speedup 1.0000x reference)
//
#include <hip/hip_runtime.h>

#define NN 20000
#define EE 320000
#define GG 50
#define IN_ 64
#define H1_ 10
#define D1_ 64
#define D2_ 128
#define F1 640   /* H1_*D1_ */
#define NEG 0.2f

static inline int cdiv(long long a, int b){ return (int)((a + b - 1) / b); }

__device__ inline float lrelu(float x){ return x > 0.f ? x : NEG * x; }
__device__ inline float wmax64(float x){
  #pragma unroll
  for(int off = 32; off > 0; off >>= 1) x = fmaxf(x, __shfl_xor(x, off, 64));
  return x;
}
__device__ inline float wsum64(float x){
  #pragma unroll
  for(int off = 32; off > 0; off >>= 1) x += __shfl_xor(x, off, 64);
  return x;
}

// ---------------- CSR build ----------------
__global__ void hist_k(const int* __restrict__ dst, int* __restrict__ hist){
  int e = blockIdx.x * blockDim.x + threadIdx.x;
  if(e < EE) atomicAdd(&hist[dst[e]], 1);
}

__global__ void scan_k(const int* __restrict__ hist, int* __restrict__ rowptr,
                       int* __restrict__ cursor){
  __shared__ int tot[1024];
  int t = threadIdx.x;
  int vals[20];
  int s = 0;
  #pragma unroll
  for(int i = 0; i < 20; i++){
    int idx = t * 20 + i;
    int v = idx < NN ? hist[idx] : 0;
    vals[i] = v; s += v;
  }
  tot[t] = s;
  __syncthreads();
  for(int off = 1; off < 1024; off <<= 1){
    int v = t >= off ? tot[t - off] : 0;
    __syncthreads();
    tot[t] += v;
    __syncthreads();
  }
  int run = tot[t] - s;
  #pragma unroll
  for(int i = 0; i < 20; i++){
    int idx = t * 20 + i;
    if(idx < NN){ rowptr[idx] = run; cursor[idx] = run; run += vals[i]; }
  }
  if(t == 1023) rowptr[NN] = tot[1023];
}

__global__ void scatter_k(const int* __restrict__ src, const int* __restrict__ dst,
                          int* __restrict__ cursor, int* __restrict__ ssrc){
  int e = blockIdx.x * blockDim.x + threadIdx.x;
  if(e >= EE) return;
  int pos = atomicAdd(&cursor[dst[e]], 1);
  ssrc[pos] = src[e];
}

// ---------------- GEMM1: ft1 = feat @ W1, fused el1/er1 ----------------
__global__ __launch_bounds__(256) void gemm1(
    const float* __restrict__ feat, const float* __restrict__ W1,
    const float* __restrict__ al1, const float* __restrict__ ar1,
    float* __restrict__ ft1, float* __restrict__ el, float* __restrict__ er){
  __shared__ float AsT[64][68];  // [k][r]
  __shared__ float Bs[64][68];   // [k][c]
  int h = blockIdx.x;
  int n0 = blockIdx.y * 64;
  int tid = threadIdx.x;
  #pragma unroll
  for(int l = 0; l < 4; l++){
    int idx = tid + l * 256;
    int r = idx >> 4, c4 = (idx & 15) << 2;
    float4 v = make_float4(0.f,0.f,0.f,0.f);
    if(n0 + r < NN) v = *(const float4*)&feat[(size_t)(n0 + r) * IN_ + c4];
    AsT[c4+0][r] = v.x; AsT[c4+1][r] = v.y; AsT[c4+2][r] = v.z; AsT[c4+3][r] = v.w;
    float4 w = *(const float4*)&W1[(size_t)(idx >> 4) * F1 + h * 64 + c4];
    *(float4*)&Bs[idx >> 4][c4] = w;
  }
  __syncthreads();
  int tr = tid >> 4, tc = tid & 15;
  float acc[4][4];
  #pragma unroll
  for(int i = 0; i < 4; i++)
    #pragma unroll
    for(int j = 0; j < 4; j++) acc[i][j] = 0.f;
  #pragma unroll 8
  for(int k = 0; k < 64; k++){
    float4 a4 = *(const float4*)&AsT[k][tr << 2];
    float4 b4 = *(const float4*)&Bs[k][tc << 2];
    float av[4] = {a4.x, a4.y, a4.z, a4.w};
    float bv[4] = {b4.x, b4.y, b4.z, b4.w};
    #pragma unroll
    for(int i = 0; i < 4; i++)
      #pragma unroll
      for(int j = 0; j < 4; j++) acc[i][j] += av[i] * bv[j];
  }
  float al4[4], ar4[4];
  #pragma unroll
  for(int j = 0; j < 4; j++){
    al4[j] = al1[h * 64 + (tc << 2) + j];
    ar4[j] = ar1[h * 64 + (tc << 2) + j];
  }
  #pragma unroll
  for(int i = 0; i < 4; i++){
    int row = n0 + (tr << 2) + i;
    bool ok = row < NN;
    if(ok){
      float4 o = make_float4(acc[i][0], acc[i][1], acc[i][2], acc[i][3]);
      *(float4*)&ft1[(size_t)row * F1 + h * 64 + (tc << 2)] = o;
    }
    float e1 = acc[i][0]*al4[0] + acc[i][1]*al4[1] + acc[i][2]*al4[2] + acc[i][3]*al4[3];
    float e2 = acc[i][0]*ar4[0] + acc[i][1]*ar4[1] + acc[i][2]*ar4[2] + acc[i][3]*ar4[3];
    #pragma unroll
    for(int off = 1; off < 16; off <<= 1){
      e1 += __shfl_xor(e1, off, 64);
      e2 += __shfl_xor(e2, off, 64);
    }
    if(tc == 0 && ok){ el[row * H1_ + h] = e1; er[row * H1_ + h] = e2; }
  }
}

// ---------------- fused attn+agg layer 1 (+bias+relu+head-sum) ----------------
// block 640 = 10 waves (wave per head); deg<=64: softmax in registers (edge=lane),
// aggregation 8 edges x 8 lanes x float8
__global__ __launch_bounds__(640) void l1_fused(
    const int* __restrict__ rowptr, const int* __restrict__ ssrc,
    const float* __restrict__ el, const float* __restrict__ er,
    const float* __restrict__ ft1, const float* __restrict__ b1,
    float* __restrict__ h1v){
  __shared__ float sdata[F1];
  int dn = blockIdx.x;
  int tid = threadIdx.x;
  int h = tid >> 6, lane = tid & 63;
  int eg = lane >> 3, dg = lane & 7;
  int base = rowptr[dn], deg = rowptr[dn + 1] - base;
  float4 acc0 = make_float4(0.f,0.f,0.f,0.f);
  float4 acc1 = make_float4(0.f,0.f,0.f,0.f);
  size_t hoff = (size_t)h * 64 + (dg << 3);

  if(deg > 0 && deg <= 64){
    float er_h = er[dn * H1_ + h];
    int sn_l = 0;
    float e_l = -INFINITY;
    if(lane < deg){
      sn_l = ssrc[base + lane];
      e_l = lrelu(el[sn_l * H1_ + h] + er_h);
    }
    float mx = wmax64(e_l);
    float p = lane < deg ? expf(e_l - mx) : 0.f;
    float av = p / wsum64(p);
    for(int i = eg; i < deg; i += 8){
      int sn_i = __shfl(sn_l, i, 64);
      float a_i = __shfl(av, i, 64);
      const float* fp = &ft1[(size_t)sn_i * F1 + hoff];
      float4 f0 = *(const float4*)fp;
      float4 f1 = *(const float4*)(fp + 4);
      acc0.x += a_i * f0.x; acc0.y += a_i * f0.y;
      acc0.z += a_i * f0.z; acc0.w += a_i * f0.w;
      acc1.x += a_i * f1.x; acc1.y += a_i * f1.y;
      acc1.z += a_i * f1.z; acc1.w += a_i * f1.w;
    }
  } else if(deg > 64){
    float er_h = er[dn * H1_ + h];
    float mx = -INFINITY;
    for(int i = lane; i < deg; i += 64)
      mx = fmaxf(mx, lrelu(el[ssrc[base + i] * H1_ + h] + er_h));
    mx = wmax64(mx);
    float sm = 0.f;
    for(int i = lane; i < deg; i += 64)
      sm += expf(lrelu(el[ssrc[base + i] * H1_ + h] + er_h) - mx);
    float inv = 1.f / wsum64(sm);
    for(int i = eg; i < deg; i += 8){
      int sn_i = ssrc[base + i];
      float a_i = expf(lrelu(el[sn_i * H1_ + h] + er_h) - mx) * inv;
      const float* fp = &ft1[(size_t)sn_i * F1 + hoff];
      float4 f0 = *(const float4*)fp;
      float4 f1 = *(const float4*)(fp + 4);
      acc0.x += a_i * f0.x; acc0.y += a_i * f0.y;
      acc0.z += a_i * f0.z; acc0.w += a_i * f0.w;
      acc1.x += a_i * f1.x; acc1.y += a_i * f1.y;
      acc1.z += a_i * f1.z; acc1.w += a_i * f1.w;
    }
  }
  #pragma unroll
  for(int off = 8; off <= 32; off <<= 1){
    acc0.x += __shfl_xor(acc0.x, off, 64); acc0.y += __shfl_xor(acc0.y, off, 64);
    acc0.z += __shfl_xor(acc0.z, off, 64); acc0.w += __shfl_xor(acc0.w, off, 64);
    acc1.x += __shfl_xor(acc1.x, off, 64); acc1.y += __shfl_xor(acc1.y, off, 64);
    acc1.z += __shfl_xor(acc1.z, off, 64); acc1.w += __shfl_xor(acc1.w, off, 64);
  }
  if(eg == 0){
    int d = h * 64 + (dg << 3);
    float v;
    v = acc0.x + b1[d+0]; sdata[d+0] = v > 0.f ? v : 0.f;
    v = acc0.y + b1[d+1]; sdata[d+1] = v > 0.f ? v : 0.f;
    v = acc0.z + b1[d+2]; sdata[d+2] = v > 0.f ? v : 0.f;
    v = acc0.w + b1[d+3]; sdata[d+3] = v > 0.f ? v : 0.f;
    v = acc1.x + b1[d+4]; sdata[d+4] = v > 0.f ? v : 0.f;
    v = acc1.y + b1[d+5]; sdata[d+5] = v > 0.f ? v : 0.f;
    v = acc1.z + b1[d+6]; sdata[d+6] = v > 0.f ? v : 0.f;
    v = acc1.w + b1[d+7]; sdata[d+7] = v > 0.f ? v : 0.f;
  }
  __syncthreads();
  if(tid < 64){
    float s = 0.f;
    #pragma unroll
    for(int hh = 0; hh < H1_; hh++) s += sdata[hh * 64 + tid];
    h1v[dn * D1_ + tid] = s;
  }
}

// ---------------- GEMM2: ft2 = h1v @ W2, fused el2/er2 ----------------
__global__ __launch_bounds__(256) void gemm2(
    const float* __restrict__ h1v, const float* __restrict__ W2,
    const float* __restrict__ al2, const float* __restrict__ ar2,
    float* __restrict__ ft2, float* __restrict__ el, float* __restrict__ er){
  __shared__ float AsT[64][36];   // [k][r], r<32
  __shared__ float Bs[64][132];   // [k][c]
  int n0 = blockIdx.x * 32;
  int tid = threadIdx.x;
  #pragma unroll
  for(int l = 0; l < 2; l++){
    int idx = tid + l * 256;
    int r = idx >> 4, c4 = (idx & 15) << 2;
    float4 v = make_float4(0.f,0.f,0.f,0.f);
    if(n0 + r < NN) v = *(const float4*)&h1v[(size_t)(n0 + r) * D1_ + c4];
    AsT[c4+0][r] = v.x; AsT[c4+1][r] = v.y; AsT[c4+2][r] = v.z; AsT[c4+3][r] = v.w;
  }
  #pragma unroll
  for(int l = 0; l < 8; l++){
    int idx = tid + l * 256;
    int k = idx >> 5, c4 = (idx & 31) << 2;
    *(float4*)&Bs[k][c4] = *(const float4*)&W2[(size_t)k * D2_ + c4];
  }
  __syncthreads();
  int tr = tid >> 5, tc = tid & 31;
  float acc[4][4];
  #pragma unroll
  for(int i = 0; i < 4; i++)
    #pragma unroll
    for(int j = 0; j < 4; j++) acc[i][j] = 0.f;
  #pragma unroll 8
  for(int k = 0; k < 64; k++){
    float4 a4 = *(const float4*)&AsT[k][tr << 2];
    float4 b4 = *(const float4*)&Bs[k][tc << 2];
    float av[4] = {a4.x, a4.y, a4.z, a4.w};
    float bv[4] = {b4.x, b4.y, b4.z, b4.w};
    #pragma unroll
    for(int i = 0; i < 4; i++)
      #pragma unroll
      for(int j = 0; j < 4; j++) acc[i][j] += av[i] * bv[j];
  }
  float al4[4], ar4[4];
  #pragma unroll
  for(int j = 0; j < 4; j++){
    al4[j] = al2[(tc << 2) + j];
    ar4[j] = ar2[(tc << 2) + j];
  }
  #pragma unroll
  for(int i = 0; i < 4; i++){
    int row = n0 + (tr << 2) + i;
    bool ok = row < NN;
    if(ok){
      float4 o = make_float4(acc[i][0], acc[i][1], acc[i][2], acc[i][3]);
      *(float4*)&ft2[(size_t)row * D2_ + (tc << 2)] = o;
    }
    float e1 = acc[i][0]*al4[0] + acc[i][1]*al4[1] + acc[i][2]*al4[2] + acc[i][3]*al4[3];
    float e2 = acc[i][0]*ar4[0] + acc[i][1]*ar4[1] + acc[i][2]*ar4[2] + acc[i][3]*ar4[3];
    #pragma unroll
    for(int off = 1; off < 32; off <<= 1){
      e1 += __shfl_xor(e1, off, 64);
      e2 += __shfl_xor(e2, off, 64);
    }
    if(tc == 0 && ok){ el[row] = e1; er[row] = e2; }
  }
}

// ---------------- fused attn+agg layer 2 (+bias+relu+graph max) ----------------
// block 128 = 2 waves (64-dim halves), softmax duplicated per wave
__global__ __launch_bounds__(128) void l2_fused(
    const int* __restrict__ rowptr, const int* __restrict__ ssrc,
    const float* __restrict__ el, const float* __restrict__ er,
    const float* __restrict__ ft2, const float* __restrict__ b2,
    const int* __restrict__ gid, int* __restrict__ rbuf){
  int dn = blockIdx.x;
  int tid = threadIdx.x;
  int w = tid >> 6, lane = tid & 63;
  int eg = lane >> 3, dg = lane & 7;
  int base = rowptr[dn], deg = rowptr[dn + 1] - base;
  float4 acc0 = make_float4(0.f,0.f,0.f,0.f);
  float4 acc1 = make_float4(0.f,0.f,0.f,0.f);
  int doff = w * 64 + (dg << 3);

  if(deg > 0 && deg <= 64){
    float er_d = er[dn];
    int sn_l = 0;
    float e_l = -INFINITY;
    if(lane < deg){
      sn_l = ssrc[base + lane];
      e_l = lrelu(el[sn_l] + er_d);
    }
    float mx = wmax64(e_l);
    float p = lane < deg ? expf(e_l - mx) : 0.f;
    float av = p / wsum64(p);
    for(int i = eg; i < deg; i += 8){
      int sn_i = __shfl(sn_l, i, 64);
      float a_i = __shfl(av, i, 64);
      const float* fp = &ft2[(size_t)sn_i * D2_ + doff];
      float4 f0 = *(const float4*)fp;
      float4 f1 = *(const float4*)(fp + 4);
      acc0.x += a_i * f0.x; acc0.y += a_i * f0.y;
      acc0.z += a_i * f0.z; acc0.w += a_i * f0.w;
      acc1.x += a_i * f1.x; acc1.y += a_i * f1.y;
      acc1.z += a_i * f1.z; acc1.w += a_i * f1.w;
    }
  } else if(deg > 64){
    float er_d = er[dn];
    float mx = -INFINITY;
    for(int i = lane; i < deg; i += 64)
      mx = fmaxf(mx, lrelu(el[ssrc[base + i]] + er_d));
    mx = wmax64(mx);
    float sm = 0.f;
    for(int i = lane; i < deg; i += 64)
      sm += expf(lrelu(el[ssrc[base + i]] + er_d) - mx);
    float inv = 1.f / wsum64(sm);
    for(int i = eg; i < deg; i += 8){
      int sn_i = ssrc[base + i];
      float a_i = expf(lrelu(el[sn_i] + er_d) - mx) * inv;
      const float* fp = &ft2[(size_t)sn_i * D2_ + doff];
      float4 f0 = *(const float4*)fp;
      float4 f1 = *(const float4*)(fp + 4);
      acc0.x += a_i * f0.x; acc0.y += a_i * f0.y;
      acc0.z += a_i * f0.z; acc0.w += a_i * f0.w;
      acc1.x += a_i * f1.x; acc1.y += a_i * f1.y;
      acc1.z += a_i * f1.z; acc1.w += a_i * f1.w;
    }
  }
  #pragma unroll
  for(int off = 8; off <= 32; off <<= 1){
    acc0.x += __shfl_xor(acc0.x, off, 64); acc0.y += __shfl_xor(acc0.y, off, 64);
    acc0.z += __shfl_xor(acc0.z, off, 64); acc0.w += __shfl_xor(acc0.w, off, 64);
    acc1.x += __shfl_xor(acc1.x, off, 64); acc1.y += __shfl_xor(acc1.y, off, 64);
    acc1.z += __shfl_xor(acc1.z, off, 64); acc1.w += __shfl_xor(acc1.w, off, 64);
  }
  if(eg == 0){
    int gb = gid[dn] * D2_ + doff;
    float v;
    v = acc0.x + b2[doff+0]; v = v > 0.f ? v : 0.f; atomicMax(&rbuf[gb+0], __float_as_int(v));
    v = acc0.y + b2[doff+1]; v = v > 0.f ? v : 0.f; atomicMax(&rbuf[gb+1], __float_as_int(v));
    v = acc0.z + b2[doff+2]; v = v > 0.f ? v : 0.f; atomicMax(&rbuf[gb+2], __float_as_int(v));
    v = acc0.w + b2[doff+3]; v = v > 0.f ? v : 0.f; atomicMax(&rbuf[gb+3], __float_as_int(v));
    v = acc1.x + b2[doff+4]; v = v > 0.f ? v : 0.f; atomicMax(&rbuf[gb+4], __float_as_int(v));
    v = acc1.y + b2[doff+5]; v = v > 0.f ? v : 0.f; atomicMax(&rbuf[gb+5], __float_as_int(v));
    v = acc1.z + b2[doff+6]; v = v > 0.f ? v : 0.f; atomicMax(&rbuf[gb+6], __float_as_int(v));
    v = acc1.w + b2[doff+7]; v = v > 0.f ? v : 0.f; atomicMax(&rbuf[gb+7], __float_as_int(v));
  }
}

__global__ void final_mlp(const float* __restrict__ r, const float* __restrict__ lw1,
                          const float* __restrict__ lb1, const float* __restrict__ lw2,
                          const float* __restrict__ lb2, float* __restrict__ out){
  __shared__ float rv[D2_];
  __shared__ float t[D2_];
  int g = blockIdx.x, j = threadIdx.x;
  rv[j] = r[g * D2_ + j];
  __syncthreads();
  float acc = lb1[j];
  #pragma unroll
  for(int k = 0; k < D2_; k++) acc += rv[k] * lw1[k * D2_ + j];
  acc = acc > 0.f ? acc : 0.f;
  t[j] = acc * lw2[j];
  __syncthreads();
  for(int off = 64; off > 0; off >>= 1){
    if(j < off) t[j] += t[j + off];
    __syncthreads();
  }
  if(j == 0){
    float v = t[0] + lb2[0];
    out[g] = v > 0.f ? v : 0.f;
  }
}

extern "C" void kernel_launch(void* const* d_in, const int* in_sizes, int n_in,
                              void* d_out, int out_size, void* d_ws, size_t ws_size,
                              hipStream_t stream) {
  const float* feat = (const float*)d_in[0];
  const int*   src  = (const int*)d_in[1];
  const int*   dst  = (const int*)d_in[2];
  const int*   gid  = (const int*)d_in[3];
  const float* W1   = (const float*)d_in[4];
  const float* al1  = (const float*)d_in[5];
  const float* ar1  = (const float*)d_in[6];
  const float* b1   = (const float*)d_in[7];
  const float* W2   = (const float*)d_in[8];
  const float* al2  = (const float*)d_in[9];
  const float* ar2  = (const float*)d_in[10];
  const float* b2   = (const float*)d_in[11];
  const float* lw1  = (const float*)d_in[12];
  const float* lb1  = (const float*)d_in[13];
  const float* lw2  = (const float*)d_in[14];
  const float* lb2  = (const float*)d_in[15];
  float* out = (float*)d_out;

  float* ws = (float*)d_ws;
  size_t o = 0;
  float* ft1  = ws + o; o += (size_t)NN * F1;     // 12.8M
  float* ft2  = ws + o; o += (size_t)NN * D2_;    // 2.56M
  float* el1  = ws + o; o += (size_t)NN * H1_;
  float* er1  = ws + o; o += (size_t)NN * H1_;
  float* h1v  = ws + o; o += (size_t)NN * D1_;
  float* el2  = ws + o; o += NN;
  float* er2  = ws + o; o += NN;
  float* rbuf = ws + o; o += (size_t)GG * D2_;
  int* hist   = (int*)(ws + o); o += NN;
  int* rowptr = (int*)(ws + o); o += NN + 1;
  int* cursor = (int*)(ws + o); o += NN;
  int* ssrc   = (int*)(ws + o); o += EE;

  // ---- CSR build ----
  hipMemsetAsync(hist, 0, (size_t)NN * 4, stream);
  hist_k<<<cdiv(EE,256),256,0,stream>>>(dst, hist);
  scan_k<<<1,1024,0,stream>>>(hist, rowptr, cursor);
  scatter_k<<<cdiv(EE,256),256,0,stream>>>(src, dst, cursor, ssrc);

  // ---- layer 1 ----
  gemm1<<<dim3(H1_, cdiv(NN,64)), 256, 0, stream>>>(feat, W1, al1, ar1, ft1, el1, er1);
  l1_fused<<<NN, 640, 0, stream>>>(rowptr, ssrc, el1, er1, ft1, b1, h1v);

  // ---- layer 2 ----
  gemm2<<<cdiv(NN,32), 256, 0, stream>>>(h1v, W2, al2, ar2, ft2, el2, er2);
  hipMemsetAsync(rbuf, 0, (size_t)GG * D2_ * 4, stream);
  l2_fused<<<NN, 128, 0, stream>>>(rowptr, ssrc, el2, er2, ft2, b2, gid, (int*)rbuf);

  // ---- readout MLP ----
  final_mlp<<<GG, D2_, 0, stream>>>(rbuf, lw1, lb1, lw2, lb2, out);
}

// Round 5
// 304.203 us; speedup vs baseline: 1.5447x; 1.5447x over previous
//
#include <hip/hip_runtime.h>

#define NN 20000
#define EE 320000
#define GG 50
#define IN_ 64
#define H1_ 10
#define D1_ 64
#define D2_ 128
#define F1 640   /* H1_*D1_ */
#define NEG 0.2f

static inline int cdiv(long long a, int b){ return (int)((a + b - 1) / b); }

__device__ inline float lrelu(float x){ return x > 0.f ? x : NEG * x; }
__device__ inline float wmax64(float x){
  #pragma unroll
  for(int off = 32; off > 0; off >>= 1) x = fmaxf(x, __shfl_xor(x, off, 64));
  return x;
}
__device__ inline float wsum64(float x){
  #pragma unroll
  for(int off = 32; off > 0; off >>= 1) x += __shfl_xor(x, off, 64);
  return x;
}

// ---------------- CSR build ----------------
__global__ void hist_k(const int* __restrict__ dst, int* __restrict__ hist){
  int e = blockIdx.x * blockDim.x + threadIdx.x;
  if(e < EE) atomicAdd(&hist[dst[e]], 1);
}

__global__ void scan_k(const int* __restrict__ hist, int* __restrict__ rowptr,
                       int* __restrict__ cursor){
  __shared__ int tot[1024];
  int t = threadIdx.x;
  int vals[20];
  int s = 0;
  #pragma unroll
  for(int i = 0; i < 20; i++){
    int idx = t * 20 + i;
    int v = idx < NN ? hist[idx] : 0;
    vals[i] = v; s += v;
  }
  tot[t] = s;
  __syncthreads();
  for(int off = 1; off < 1024; off <<= 1){
    int v = t >= off ? tot[t - off] : 0;
    __syncthreads();
    tot[t] += v;
    __syncthreads();
  }
  int run = tot[t] - s;
  #pragma unroll
  for(int i = 0; i < 20; i++){
    int idx = t * 20 + i;
    if(idx < NN){ rowptr[idx] = run; cursor[idx] = run; run += vals[i]; }
  }
  if(t == 1023) rowptr[NN] = tot[1023];
}

__global__ void scatter_k(const int* __restrict__ src, const int* __restrict__ dst,
                          int* __restrict__ cursor, int* __restrict__ ssrc){
  int e = blockIdx.x * blockDim.x + threadIdx.x;
  if(e >= EE) return;
  int pos = atomicAdd(&cursor[dst[e]], 1);
  ssrc[pos] = src[e];
}

// ---------------- GEMM1: ft1 = feat @ W1, fused el1/er1 ----------------
__global__ __launch_bounds__(256) void gemm1(
    const float* __restrict__ feat, const float* __restrict__ W1,
    const float* __restrict__ al1, const float* __restrict__ ar1,
    float* __restrict__ ft1, float* __restrict__ el, float* __restrict__ er){
  __shared__ float AsT[64][68];  // [k][r]
  __shared__ float Bs[64][68];   // [k][c]
  int h = blockIdx.x;
  int n0 = blockIdx.y * 64;
  int tid = threadIdx.x;
  #pragma unroll
  for(int l = 0; l < 4; l++){
    int idx = tid + l * 256;
    int r = idx >> 4, c4 = (idx & 15) << 2;
    float4 v = make_float4(0.f,0.f,0.f,0.f);
    if(n0 + r < NN) v = *(const float4*)&feat[(size_t)(n0 + r) * IN_ + c4];
    AsT[c4+0][r] = v.x; AsT[c4+1][r] = v.y; AsT[c4+2][r] = v.z; AsT[c4+3][r] = v.w;
    float4 w = *(const float4*)&W1[(size_t)(idx >> 4) * F1 + h * 64 + c4];
    *(float4*)&Bs[idx >> 4][c4] = w;
  }
  __syncthreads();
  int tr = tid >> 4, tc = tid & 15;
  float acc[4][4];
  #pragma unroll
  for(int i = 0; i < 4; i++)
    #pragma unroll
    for(int j = 0; j < 4; j++) acc[i][j] = 0.f;
  #pragma unroll 8
  for(int k = 0; k < 64; k++){
    float4 a4 = *(const float4*)&AsT[k][tr << 2];
    float4 b4 = *(const float4*)&Bs[k][tc << 2];
    float av[4] = {a4.x, a4.y, a4.z, a4.w};
    float bv[4] = {b4.x, b4.y, b4.z, b4.w};
    #pragma unroll
    for(int i = 0; i < 4; i++)
      #pragma unroll
      for(int j = 0; j < 4; j++) acc[i][j] += av[i] * bv[j];
  }
  float al4[4], ar4[4];
  #pragma unroll
  for(int j = 0; j < 4; j++){
    al4[j] = al1[h * 64 + (tc << 2) + j];
    ar4[j] = ar1[h * 64 + (tc << 2) + j];
  }
  #pragma unroll
  for(int i = 0; i < 4; i++){
    int row = n0 + (tr << 2) + i;
    bool ok = row < NN;
    if(ok){
      float4 o = make_float4(acc[i][0], acc[i][1], acc[i][2], acc[i][3]);
      *(float4*)&ft1[(size_t)row * F1 + h * 64 + (tc << 2)] = o;
    }
    float e1 = acc[i][0]*al4[0] + acc[i][1]*al4[1] + acc[i][2]*al4[2] + acc[i][3]*al4[3];
    float e2 = acc[i][0]*ar4[0] + acc[i][1]*ar4[1] + acc[i][2]*ar4[2] + acc[i][3]*ar4[3];
    #pragma unroll
    for(int off = 1; off < 16; off <<= 1){
      e1 += __shfl_xor(e1, off, 64);
      e2 += __shfl_xor(e2, off, 64);
    }
    if(tc == 0 && ok){ el[row * H1_ + h] = e1; er[row * H1_ + h] = e2; }
  }
}

// ---------------- fused attn+agg layer 1 (+bias+relu+head-sum) ----------------
__global__ __launch_bounds__(640) void l1_fused(
    const int* __restrict__ rowptr, const int* __restrict__ ssrc,
    const float* __restrict__ el, const float* __restrict__ er,
    const float* __restrict__ ft1, const float* __restrict__ b1,
    float* __restrict__ h1v){
  __shared__ float sdata[F1];
  int dn = blockIdx.x;
  int tid = threadIdx.x;
  int h = tid >> 6, lane = tid & 63;
  int eg = lane >> 3, dg = lane & 7;
  int base = rowptr[dn], deg = rowptr[dn + 1] - base;
  float4 acc0 = make_float4(0.f,0.f,0.f,0.f);
  float4 acc1 = make_float4(0.f,0.f,0.f,0.f);
  size_t hoff = (size_t)h * 64 + (dg << 3);

  if(deg > 0 && deg <= 64){
    float er_h = er[dn * H1_ + h];
    int sn_l = 0;
    float e_l = -INFINITY;
    if(lane < deg){
      sn_l = ssrc[base + lane];
      e_l = lrelu(el[sn_l * H1_ + h] + er_h);
    }
    float mx = wmax64(e_l);
    float p = lane < deg ? expf(e_l - mx) : 0.f;
    float av = p / wsum64(p);
    for(int i = eg; i < deg; i += 8){
      int sn_i = __shfl(sn_l, i, 64);
      float a_i = __shfl(av, i, 64);
      const float* fp = &ft1[(size_t)sn_i * F1 + hoff];
      float4 f0 = *(const float4*)fp;
      float4 f1 = *(const float4*)(fp + 4);
      acc0.x += a_i * f0.x; acc0.y += a_i * f0.y;
      acc0.z += a_i * f0.z; acc0.w += a_i * f0.w;
      acc1.x += a_i * f1.x; acc1.y += a_i * f1.y;
      acc1.z += a_i * f1.z; acc1.w += a_i * f1.w;
    }
  } else if(deg > 64){
    float er_h = er[dn * H1_ + h];
    float mx = -INFINITY;
    for(int i = lane; i < deg; i += 64)
      mx = fmaxf(mx, lrelu(el[ssrc[base + i] * H1_ + h] + er_h));
    mx = wmax64(mx);
    float sm = 0.f;
    for(int i = lane; i < deg; i += 64)
      sm += expf(lrelu(el[ssrc[base + i] * H1_ + h] + er_h) - mx);
    float inv = 1.f / wsum64(sm);
    for(int i = eg; i < deg; i += 8){
      int sn_i = ssrc[base + i];
      float a_i = expf(lrelu(el[sn_i * H1_ + h] + er_h) - mx) * inv;
      const float* fp = &ft1[(size_t)sn_i * F1 + hoff];
      float4 f0 = *(const float4*)fp;
      float4 f1 = *(const float4*)(fp + 4);
      acc0.x += a_i * f0.x; acc0.y += a_i * f0.y;
      acc0.z += a_i * f0.z; acc0.w += a_i * f0.w;
      acc1.x += a_i * f1.x; acc1.y += a_i * f1.y;
      acc1.z += a_i * f1.z; acc1.w += a_i * f1.w;
    }
  }
  #pragma unroll
  for(int off = 8; off <= 32; off <<= 1){
    acc0.x += __shfl_xor(acc0.x, off, 64); acc0.y += __shfl_xor(acc0.y, off, 64);
    acc0.z += __shfl_xor(acc0.z, off, 64); acc0.w += __shfl_xor(acc0.w, off, 64);
    acc1.x += __shfl_xor(acc1.x, off, 64); acc1.y += __shfl_xor(acc1.y, off, 64);
    acc1.z += __shfl_xor(acc1.z, off, 64); acc1.w += __shfl_xor(acc1.w, off, 64);
  }
  if(eg == 0){
    int d = h * 64 + (dg << 3);
    float v;
    v = acc0.x + b1[d+0]; sdata[d+0] = v > 0.f ? v : 0.f;
    v = acc0.y + b1[d+1]; sdata[d+1] = v > 0.f ? v : 0.f;
    v = acc0.z + b1[d+2]; sdata[d+2] = v > 0.f ? v : 0.f;
    v = acc0.w + b1[d+3]; sdata[d+3] = v > 0.f ? v : 0.f;
    v = acc1.x + b1[d+4]; sdata[d+4] = v > 0.f ? v : 0.f;
    v = acc1.y + b1[d+5]; sdata[d+5] = v > 0.f ? v : 0.f;
    v = acc1.z + b1[d+6]; sdata[d+6] = v > 0.f ? v : 0.f;
    v = acc1.w + b1[d+7]; sdata[d+7] = v > 0.f ? v : 0.f;
  }
  __syncthreads();
  if(tid < 64){
    float s = 0.f;
    #pragma unroll
    for(int hh = 0; hh < H1_; hh++) s += sdata[hh * 64 + tid];
    h1v[dn * D1_ + tid] = s;
  }
}

// ---------------- GEMM2: ft2 = h1v @ W2, fused el2/er2 ----------------
__global__ __launch_bounds__(256) void gemm2(
    const float* __restrict__ h1v, const float* __restrict__ W2,
    const float* __restrict__ al2, const float* __restrict__ ar2,
    float* __restrict__ ft2, float* __restrict__ el, float* __restrict__ er){
  __shared__ float AsT[64][36];   // [k][r], r<32
  __shared__ float Bs[64][132];   // [k][c]
  int n0 = blockIdx.x * 32;
  int tid = threadIdx.x;
  #pragma unroll
  for(int l = 0; l < 2; l++){
    int idx = tid + l * 256;
    int r = idx >> 4, c4 = (idx & 15) << 2;
    float4 v = make_float4(0.f,0.f,0.f,0.f);
    if(n0 + r < NN) v = *(const float4*)&h1v[(size_t)(n0 + r) * D1_ + c4];
    AsT[c4+0][r] = v.x; AsT[c4+1][r] = v.y; AsT[c4+2][r] = v.z; AsT[c4+3][r] = v.w;
  }
  #pragma unroll
  for(int l = 0; l < 8; l++){
    int idx = tid + l * 256;
    int k = idx >> 5, c4 = (idx & 31) << 2;
    *(float4*)&Bs[k][c4] = *(const float4*)&W2[(size_t)k * D2_ + c4];
  }
  __syncthreads();
  int tr = tid >> 5, tc = tid & 31;
  float acc[4][4];
  #pragma unroll
  for(int i = 0; i < 4; i++)
    #pragma unroll
    for(int j = 0; j < 4; j++) acc[i][j] = 0.f;
  #pragma unroll 8
  for(int k = 0; k < 64; k++){
    float4 a4 = *(const float4*)&AsT[k][tr << 2];
    float4 b4 = *(const float4*)&Bs[k][tc << 2];
    float av[4] = {a4.x, a4.y, a4.z, a4.w};
    float bv[4] = {b4.x, b4.y, b4.z, b4.w};
    #pragma unroll
    for(int i = 0; i < 4; i++)
      #pragma unroll
      for(int j = 0; j < 4; j++) acc[i][j] += av[i] * bv[j];
  }
  float al4[4], ar4[4];
  #pragma unroll
  for(int j = 0; j < 4; j++){
    al4[j] = al2[(tc << 2) + j];
    ar4[j] = ar2[(tc << 2) + j];
  }
  #pragma unroll
  for(int i = 0; i < 4; i++){
    int row = n0 + (tr << 2) + i;
    bool ok = row < NN;
    if(ok){
      float4 o = make_float4(acc[i][0], acc[i][1], acc[i][2], acc[i][3]);
      *(float4*)&ft2[(size_t)row * D2_ + (tc << 2)] = o;
    }
    float e1 = acc[i][0]*al4[0] + acc[i][1]*al4[1] + acc[i][2]*al4[2] + acc[i][3]*al4[3];
    float e2 = acc[i][0]*ar4[0] + acc[i][1]*ar4[1] + acc[i][2]*ar4[2] + acc[i][3]*ar4[3];
    #pragma unroll
    for(int off = 1; off < 32; off <<= 1){
      e1 += __shfl_xor(e1, off, 64);
      e2 += __shfl_xor(e2, off, 64);
    }
    if(tc == 0 && ok){ el[row] = e1; er[row] = e2; }
  }
}

// ---------------- fused attn+agg layer 2 (+bias+relu) -> dense h2 ----------------
// block 128 = 2 waves (64-dim halves); NO atomics — plain coalesced store
__global__ __launch_bounds__(128) void l2_fused(
    const int* __restrict__ rowptr, const int* __restrict__ ssrc,
    const float* __restrict__ el, const float* __restrict__ er,
    const float* __restrict__ ft2, const float* __restrict__ b2,
    float* __restrict__ h2v){
  int dn = blockIdx.x;
  int tid = threadIdx.x;
  int w = tid >> 6, lane = tid & 63;
  int eg = lane >> 3, dg = lane & 7;
  int base = rowptr[dn], deg = rowptr[dn + 1] - base;
  float4 acc0 = make_float4(0.f,0.f,0.f,0.f);
  float4 acc1 = make_float4(0.f,0.f,0.f,0.f);
  int doff = w * 64 + (dg << 3);

  if(deg > 0 && deg <= 64){
    float er_d = er[dn];
    int sn_l = 0;
    float e_l = -INFINITY;
    if(lane < deg){
      sn_l = ssrc[base + lane];
      e_l = lrelu(el[sn_l] + er_d);
    }
    float mx = wmax64(e_l);
    float p = lane < deg ? expf(e_l - mx) : 0.f;
    float av = p / wsum64(p);
    for(int i = eg; i < deg; i += 8){
      int sn_i = __shfl(sn_l, i, 64);
      float a_i = __shfl(av, i, 64);
      const float* fp = &ft2[(size_t)sn_i * D2_ + doff];
      float4 f0 = *(const float4*)fp;
      float4 f1 = *(const float4*)(fp + 4);
      acc0.x += a_i * f0.x; acc0.y += a_i * f0.y;
      acc0.z += a_i * f0.z; acc0.w += a_i * f0.w;
      acc1.x += a_i * f1.x; acc1.y += a_i * f1.y;
      acc1.z += a_i * f1.z; acc1.w += a_i * f1.w;
    }
  } else if(deg > 64){
    float er_d = er[dn];
    float mx = -INFINITY;
    for(int i = lane; i < deg; i += 64)
      mx = fmaxf(mx, lrelu(el[ssrc[base + i]] + er_d));
    mx = wmax64(mx);
    float sm = 0.f;
    for(int i = lane; i < deg; i += 64)
      sm += expf(lrelu(el[ssrc[base + i]] + er_d) - mx);
    float inv = 1.f / wsum64(sm);
    for(int i = eg; i < deg; i += 8){
      int sn_i = ssrc[base + i];
      float a_i = expf(lrelu(el[sn_i] + er_d) - mx) * inv;
      const float* fp = &ft2[(size_t)sn_i * D2_ + doff];
      float4 f0 = *(const float4*)fp;
      float4 f1 = *(const float4*)(fp + 4);
      acc0.x += a_i * f0.x; acc0.y += a_i * f0.y;
      acc0.z += a_i * f0.z; acc0.w += a_i * f0.w;
      acc1.x += a_i * f1.x; acc1.y += a_i * f1.y;
      acc1.z += a_i * f1.z; acc1.w += a_i * f1.w;
    }
  }
  #pragma unroll
  for(int off = 8; off <= 32; off <<= 1){
    acc0.x += __shfl_xor(acc0.x, off, 64); acc0.y += __shfl_xor(acc0.y, off, 64);
    acc0.z += __shfl_xor(acc0.z, off, 64); acc0.w += __shfl_xor(acc0.w, off, 64);
    acc1.x += __shfl_xor(acc1.x, off, 64); acc1.y += __shfl_xor(acc1.y, off, 64);
    acc1.z += __shfl_xor(acc1.z, off, 64); acc1.w += __shfl_xor(acc1.w, off, 64);
  }
  if(eg == 0){
    float* op = &h2v[(size_t)dn * D2_ + doff];
    float4 o0, o1;
    o0.x = fmaxf(acc0.x + b2[doff+0], 0.f);
    o0.y = fmaxf(acc0.y + b2[doff+1], 0.f);
    o0.z = fmaxf(acc0.z + b2[doff+2], 0.f);
    o0.w = fmaxf(acc0.w + b2[doff+3], 0.f);
    o1.x = fmaxf(acc1.x + b2[doff+4], 0.f);
    o1.y = fmaxf(acc1.y + b2[doff+5], 0.f);
    o1.z = fmaxf(acc1.z + b2[doff+6], 0.f);
    o1.w = fmaxf(acc1.w + b2[doff+7], 0.f);
    *(float4*)op = o0;
    *(float4*)(op + 4) = o1;
  }
}

// ---------------- per-graph max readout (graph_ids sorted) ----------------
// grid (GG, 4): each block handles one quarter of its graph's node range.
// h2v >= 0, rbuf pre-zeroed -> int atomicMax is exact; only 50*4*128 atomics.
__global__ __launch_bounds__(128) void graph_max(
    const float* __restrict__ h2v, const int* __restrict__ gid,
    int* __restrict__ rbuf){
  __shared__ int sb[2];
  int g = blockIdx.x, c = blockIdx.y, d = threadIdx.x;
  if(d < 2){
    int tgt = g + d;  // lower_bound(gid, tgt)
    int lo = 0, hi = NN;
    while(lo < hi){ int mid = (lo + hi) >> 1; if(gid[mid] < tgt) lo = mid + 1; else hi = mid; }
    sb[d] = lo;
  }
  __syncthreads();
  int gs = sb[0], ge = sb[1];
  int len = ge - gs;
  int cs = gs + (int)((long long)len * c / 4);
  int ce = gs + (int)((long long)len * (c + 1) / 4);
  float m0 = 0.f, m1 = 0.f, m2 = 0.f, m3 = 0.f;
  int n = cs;
  for(; n + 3 < ce; n += 4){
    m0 = fmaxf(m0, h2v[(size_t)(n + 0) * D2_ + d]);
    m1 = fmaxf(m1, h2v[(size_t)(n + 1) * D2_ + d]);
    m2 = fmaxf(m2, h2v[(size_t)(n + 2) * D2_ + d]);
    m3 = fmaxf(m3, h2v[(size_t)(n + 3) * D2_ + d]);
  }
  for(; n < ce; n++) m0 = fmaxf(m0, h2v[(size_t)n * D2_ + d]);
  float m = fmaxf(fmaxf(m0, m1), fmaxf(m2, m3));
  atomicMax(&rbuf[g * D2_ + d], __float_as_int(m));
}

__global__ void final_mlp(const float* __restrict__ r, const float* __restrict__ lw1,
                          const float* __restrict__ lb1, const float* __restrict__ lw2,
                          const float* __restrict__ lb2, float* __restrict__ out){
  __shared__ float rv[D2_];
  __shared__ float t[D2_];
  int g = blockIdx.x, j = threadIdx.x;
  rv[j] = r[g * D2_ + j];
  __syncthreads();
  float acc = lb1[j];
  #pragma unroll
  for(int k = 0; k < D2_; k++) acc += rv[k] * lw1[k * D2_ + j];
  acc = acc > 0.f ? acc : 0.f;
  t[j] = acc * lw2[j];
  __syncthreads();
  for(int off = 64; off > 0; off >>= 1){
    if(j < off) t[j] += t[j + off];
    __syncthreads();
  }
  if(j == 0){
    float v = t[0] + lb2[0];
    out[g] = v > 0.f ? v : 0.f;
  }
}

extern "C" void kernel_launch(void* const* d_in, const int* in_sizes, int n_in,
                              void* d_out, int out_size, void* d_ws, size_t ws_size,
                              hipStream_t stream) {
  const float* feat = (const float*)d_in[0];
  const int*   src  = (const int*)d_in[1];
  const int*   dst  = (const int*)d_in[2];
  const int*   gid  = (const int*)d_in[3];
  const float* W1   = (const float*)d_in[4];
  const float* al1  = (const float*)d_in[5];
  const float* ar1  = (const float*)d_in[6];
  const float* b1   = (const float*)d_in[7];
  const float* W2   = (const float*)d_in[8];
  const float* al2  = (const float*)d_in[9];
  const float* ar2  = (const float*)d_in[10];
  const float* b2   = (const float*)d_in[11];
  const float* lw1  = (const float*)d_in[12];
  const float* lb1  = (const float*)d_in[13];
  const float* lw2  = (const float*)d_in[14];
  const float* lb2  = (const float*)d_in[15];
  float* out = (float*)d_out;

  float* ws = (float*)d_ws;
  size_t o = 0;
  float* ft1  = ws + o; o += (size_t)NN * F1;     // 12.8M
  float* ft2  = ws + o; o += (size_t)NN * D2_;    // 2.56M
  float* h2v  = ws + o; o += (size_t)NN * D2_;    // 2.56M
  float* el1  = ws + o; o += (size_t)NN * H1_;
  float* er1  = ws + o; o += (size_t)NN * H1_;
  float* h1v  = ws + o; o += (size_t)NN * D1_;
  float* el2  = ws + o; o += NN;
  float* er2  = ws + o; o += NN;
  float* rbuf = ws + o; o += (size_t)GG * D2_;
  int* hist   = (int*)(ws + o); o += NN;
  int* rowptr = (int*)(ws + o); o += NN + 1;
  int* cursor = (int*)(ws + o); o += NN;
  int* ssrc   = (int*)(ws + o); o += EE;

  // ---- CSR build ----
  hipMemsetAsync(hist, 0, (size_t)NN * 4, stream);
  hist_k<<<cdiv(EE,256),256,0,stream>>>(dst, hist);
  scan_k<<<1,1024,0,stream>>>(hist, rowptr, cursor);
  scatter_k<<<cdiv(EE,256),256,0,stream>>>(src, dst, cursor, ssrc);

  // ---- layer 1 ----
  gemm1<<<dim3(H1_, cdiv(NN,64)), 256, 0, stream>>>(feat, W1, al1, ar1, ft1, el1, er1);
  l1_fused<<<NN, 640, 0, stream>>>(rowptr, ssrc, el1, er1, ft1, b1, h1v);

  // ---- layer 2 ----
  gemm2<<<cdiv(NN,32), 256, 0, stream>>>(h1v, W2, al2, ar2, ft2, el2, er2);
  l2_fused<<<NN, 128, 0, stream>>>(rowptr, ssrc, el2, er2, ft2, b2, h2v);

  // ---- readout + MLP ----
  hipMemsetAsync(rbuf, 0, (size_t)GG * D2_ * 4, stream);
  graph_max<<<dim3(GG, 4), 128, 0, stream>>>(h2v, gid, (int*)rbuf);
  final_mlp<<<GG, D2_, 0, stream>>>(rbuf, lw1, lb1, lw2, lb2, out);
}

// Round 6
// 268.505 us; speedup vs baseline: 1.7501x; 1.1329x over previous
//
#include <hip/hip_runtime.h>

#define NN 20000
#define EE 320000
#define GG 50
#define IN_ 64
#define H1_ 10
#define D1_ 64
#define D2_ 128
#define F1 640   /* H1_*D1_ */
#define NEG 0.2f

static inline int cdiv(long long a, int b){ return (int)((a + b - 1) / b); }

__device__ inline float lrelu(float x){ return x > 0.f ? x : NEG * x; }
__device__ inline float wmax64(float x){
  #pragma unroll
  for(int off = 32; off > 0; off >>= 1) x = fmaxf(x, __shfl_xor(x, off, 64));
  return x;
}
__device__ inline float wsum64(float x){
  #pragma unroll
  for(int off = 32; off > 0; off >>= 1) x += __shfl_xor(x, off, 64);
  return x;
}

// ---------------- CSR build ----------------
__global__ void hist_k(const int* __restrict__ dst, int* __restrict__ hist){
  int e = blockIdx.x * blockDim.x + threadIdx.x;
  if(e < EE) atomicAdd(&hist[dst[e]], 1);
}

__global__ void scan_k(const int* __restrict__ hist, int* __restrict__ rowptr,
                       int* __restrict__ cursor){
  __shared__ int tot[1024];
  int t = threadIdx.x;
  int vals[20];
  int s = 0;
  #pragma unroll
  for(int i = 0; i < 20; i++){
    int idx = t * 20 + i;
    int v = idx < NN ? hist[idx] : 0;
    vals[i] = v; s += v;
  }
  tot[t] = s;
  __syncthreads();
  for(int off = 1; off < 1024; off <<= 1){
    int v = t >= off ? tot[t - off] : 0;
    __syncthreads();
    tot[t] += v;
    __syncthreads();
  }
  int run = tot[t] - s;
  #pragma unroll
  for(int i = 0; i < 20; i++){
    int idx = t * 20 + i;
    if(idx < NN){ rowptr[idx] = run; cursor[idx] = run; run += vals[i]; }
  }
  if(t == 1023) rowptr[NN] = tot[1023];
}

__global__ void scatter_k(const int* __restrict__ src, const int* __restrict__ dst,
                          int* __restrict__ cursor, int* __restrict__ ssrc){
  int e = blockIdx.x * blockDim.x + threadIdx.x;
  if(e >= EE) return;
  int pos = atomicAdd(&cursor[dst[e]], 1);
  ssrc[pos] = src[e];
}

// ---------------- GEMM1: ft1 = feat @ W1, fused el1/er1 ----------------
__global__ __launch_bounds__(256) void gemm1(
    const float* __restrict__ feat, const float* __restrict__ W1,
    const float* __restrict__ al1, const float* __restrict__ ar1,
    float* __restrict__ ft1, float* __restrict__ el, float* __restrict__ er){
  __shared__ float AsT[64][68];  // [k][r]
  __shared__ float Bs[64][68];   // [k][c]
  int h = blockIdx.x;
  int n0 = blockIdx.y * 64;
  int tid = threadIdx.x;
  #pragma unroll
  for(int l = 0; l < 4; l++){
    int idx = tid + l * 256;
    int r = idx >> 4, c4 = (idx & 15) << 2;
    float4 v = make_float4(0.f,0.f,0.f,0.f);
    if(n0 + r < NN) v = *(const float4*)&feat[(size_t)(n0 + r) * IN_ + c4];
    AsT[c4+0][r] = v.x; AsT[c4+1][r] = v.y; AsT[c4+2][r] = v.z; AsT[c4+3][r] = v.w;
    float4 w = *(const float4*)&W1[(size_t)(idx >> 4) * F1 + h * 64 + c4];
    *(float4*)&Bs[idx >> 4][c4] = w;
  }
  __syncthreads();
  int tr = tid >> 4, tc = tid & 15;
  float acc[4][4];
  #pragma unroll
  for(int i = 0; i < 4; i++)
    #pragma unroll
    for(int j = 0; j < 4; j++) acc[i][j] = 0.f;
  #pragma unroll 8
  for(int k = 0; k < 64; k++){
    float4 a4 = *(const float4*)&AsT[k][tr << 2];
    float4 b4 = *(const float4*)&Bs[k][tc << 2];
    float av[4] = {a4.x, a4.y, a4.z, a4.w};
    float bv[4] = {b4.x, b4.y, b4.z, b4.w};
    #pragma unroll
    for(int i = 0; i < 4; i++)
      #pragma unroll
      for(int j = 0; j < 4; j++) acc[i][j] += av[i] * bv[j];
  }
  float al4[4], ar4[4];
  #pragma unroll
  for(int j = 0; j < 4; j++){
    al4[j] = al1[h * 64 + (tc << 2) + j];
    ar4[j] = ar1[h * 64 + (tc << 2) + j];
  }
  #pragma unroll
  for(int i = 0; i < 4; i++){
    int row = n0 + (tr << 2) + i;
    bool ok = row < NN;
    if(ok){
      float4 o = make_float4(acc[i][0], acc[i][1], acc[i][2], acc[i][3]);
      *(float4*)&ft1[(size_t)row * F1 + h * 64 + (tc << 2)] = o;
    }
    float e1 = acc[i][0]*al4[0] + acc[i][1]*al4[1] + acc[i][2]*al4[2] + acc[i][3]*al4[3];
    float e2 = acc[i][0]*ar4[0] + acc[i][1]*ar4[1] + acc[i][2]*ar4[2] + acc[i][3]*ar4[3];
    #pragma unroll
    for(int off = 1; off < 16; off <<= 1){
      e1 += __shfl_xor(e1, off, 64);
      e2 += __shfl_xor(e2, off, 64);
    }
    if(tc == 0 && ok){ el[row * H1_ + h] = e1; er[row * H1_ + h] = e2; }
  }
}

// ---------------- layer-1 attn+agg, XCD-pinned per head ----------------
// blockIdx.x % 8 = XCD (round-robin heuristic). Phase A (slot<5000): head=xcd.
// Phase B: head 8 -> xcd 0..3, head 9 -> xcd 4..7. Each block: 4 waves, 1 dn each.
// Stores relu(agg + b1) per (dn, h); head-sum done by sum_heads.
__global__ __launch_bounds__(256) void l1_head(
    const int* __restrict__ rowptr, const int* __restrict__ ssrc,
    const float* __restrict__ el, const float* __restrict__ er,
    const float* __restrict__ ft1, const float* __restrict__ b1,
    float* __restrict__ out1){
  int b = blockIdx.x;
  int xcd = b & 7, slot = b >> 3;
  int h, chunk;
  if(slot < 5000){ h = xcd; chunk = slot; }
  else { int s = slot - 5000; h = 8 + (xcd >> 2); chunk = (xcd & 3) * 1250 + s; }
  int wave = threadIdx.x >> 6, lane = threadIdx.x & 63;
  int eg = lane >> 3, dg = lane & 7;
  int dn = chunk * 4 + wave;
  int base = rowptr[dn], deg = rowptr[dn + 1] - base;
  float4 acc0 = make_float4(0.f,0.f,0.f,0.f);
  float4 acc1 = make_float4(0.f,0.f,0.f,0.f);
  size_t foff = (size_t)h * 64 + (dg << 3);

  if(deg > 0 && deg <= 64){
    float er_h = er[dn * H1_ + h];
    int sn_l = 0;
    float e_l = -INFINITY;
    if(lane < deg){
      sn_l = ssrc[base + lane];
      e_l = lrelu(el[sn_l * H1_ + h] + er_h);
    }
    float mx = wmax64(e_l);
    float p = lane < deg ? expf(e_l - mx) : 0.f;
    float av = p / wsum64(p);
    for(int i = eg; i < deg; i += 8){
      int sn_i = __shfl(sn_l, i, 64);
      float a_i = __shfl(av, i, 64);
      const float* fp = &ft1[(size_t)sn_i * F1 + foff];
      float4 f0 = *(const float4*)fp;
      float4 f1 = *(const float4*)(fp + 4);
      acc0.x += a_i * f0.x; acc0.y += a_i * f0.y;
      acc0.z += a_i * f0.z; acc0.w += a_i * f0.w;
      acc1.x += a_i * f1.x; acc1.y += a_i * f1.y;
      acc1.z += a_i * f1.z; acc1.w += a_i * f1.w;
    }
  } else if(deg > 64){
    float er_h = er[dn * H1_ + h];
    float mx = -INFINITY;
    for(int i = lane; i < deg; i += 64)
      mx = fmaxf(mx, lrelu(el[ssrc[base + i] * H1_ + h] + er_h));
    mx = wmax64(mx);
    float sm = 0.f;
    for(int i = lane; i < deg; i += 64)
      sm += expf(lrelu(el[ssrc[base + i] * H1_ + h] + er_h) - mx);
    float inv = 1.f / wsum64(sm);
    for(int i = eg; i < deg; i += 8){
      int sn_i = ssrc[base + i];
      float a_i = expf(lrelu(el[sn_i * H1_ + h] + er_h) - mx) * inv;
      const float* fp = &ft1[(size_t)sn_i * F1 + foff];
      float4 f0 = *(const float4*)fp;
      float4 f1 = *(const float4*)(fp + 4);
      acc0.x += a_i * f0.x; acc0.y += a_i * f0.y;
      acc0.z += a_i * f0.z; acc0.w += a_i * f0.w;
      acc1.x += a_i * f1.x; acc1.y += a_i * f1.y;
      acc1.z += a_i * f1.z; acc1.w += a_i * f1.w;
    }
  }
  #pragma unroll
  for(int off = 8; off <= 32; off <<= 1){
    acc0.x += __shfl_xor(acc0.x, off, 64); acc0.y += __shfl_xor(acc0.y, off, 64);
    acc0.z += __shfl_xor(acc0.z, off, 64); acc0.w += __shfl_xor(acc0.w, off, 64);
    acc1.x += __shfl_xor(acc1.x, off, 64); acc1.y += __shfl_xor(acc1.y, off, 64);
    acc1.z += __shfl_xor(acc1.z, off, 64); acc1.w += __shfl_xor(acc1.w, off, 64);
  }
  if(eg == 0){
    int d = dg << 3;
    const float* bp = &b1[h * 64 + d];
    float4 o0, o1;
    o0.x = fmaxf(acc0.x + bp[0], 0.f);
    o0.y = fmaxf(acc0.y + bp[1], 0.f);
    o0.z = fmaxf(acc0.z + bp[2], 0.f);
    o0.w = fmaxf(acc0.w + bp[3], 0.f);
    o1.x = fmaxf(acc1.x + bp[4], 0.f);
    o1.y = fmaxf(acc1.y + bp[5], 0.f);
    o1.z = fmaxf(acc1.z + bp[6], 0.f);
    o1.w = fmaxf(acc1.w + bp[7], 0.f);
    float* op = &out1[(size_t)dn * F1 + h * 64 + d];
    *(float4*)op = o0;
    *(float4*)(op + 4) = o1;
  }
}

// h1v[n][d] = sum_h out1[n][h][d] (already relu'd+biased)
__global__ void sum_heads(const float* __restrict__ out1, float* __restrict__ h1v){
  int t = blockIdx.x * blockDim.x + threadIdx.x;
  if(t >= NN * 16) return;
  int n = t >> 4, d4 = (t & 15) << 2;
  float4 s = make_float4(0.f,0.f,0.f,0.f);
  #pragma unroll
  for(int h = 0; h < H1_; h++){
    float4 v = *(const float4*)&out1[(size_t)n * F1 + h * 64 + d4];
    s.x += v.x; s.y += v.y; s.z += v.z; s.w += v.w;
  }
  *(float4*)&h1v[n * D1_ + d4] = s;
}

// ---------------- GEMM2: ft2 = h1v @ W2, fused el2/er2 ----------------
__global__ __launch_bounds__(256) void gemm2(
    const float* __restrict__ h1v, const float* __restrict__ W2,
    const float* __restrict__ al2, const float* __restrict__ ar2,
    float* __restrict__ ft2, float* __restrict__ el, float* __restrict__ er){
  __shared__ float AsT[64][36];   // [k][r], r<32
  __shared__ float Bs[64][132];   // [k][c]
  int n0 = blockIdx.x * 32;
  int tid = threadIdx.x;
  #pragma unroll
  for(int l = 0; l < 2; l++){
    int idx = tid + l * 256;
    int r = idx >> 4, c4 = (idx & 15) << 2;
    float4 v = make_float4(0.f,0.f,0.f,0.f);
    if(n0 + r < NN) v = *(const float4*)&h1v[(size_t)(n0 + r) * D1_ + c4];
    AsT[c4+0][r] = v.x; AsT[c4+1][r] = v.y; AsT[c4+2][r] = v.z; AsT[c4+3][r] = v.w;
  }
  #pragma unroll
  for(int l = 0; l < 8; l++){
    int idx = tid + l * 256;
    int k = idx >> 5, c4 = (idx & 31) << 2;
    *(float4*)&Bs[k][c4] = *(const float4*)&W2[(size_t)k * D2_ + c4];
  }
  __syncthreads();
  int tr = tid >> 5, tc = tid & 31;
  float acc[4][4];
  #pragma unroll
  for(int i = 0; i < 4; i++)
    #pragma unroll
    for(int j = 0; j < 4; j++) acc[i][j] = 0.f;
  #pragma unroll 8
  for(int k = 0; k < 64; k++){
    float4 a4 = *(const float4*)&AsT[k][tr << 2];
    float4 b4 = *(const float4*)&Bs[k][tc << 2];
    float av[4] = {a4.x, a4.y, a4.z, a4.w};
    float bv[4] = {b4.x, b4.y, b4.z, b4.w};
    #pragma unroll
    for(int i = 0; i < 4; i++)
      #pragma unroll
      for(int j = 0; j < 4; j++) acc[i][j] += av[i] * bv[j];
  }
  float al4[4], ar4[4];
  #pragma unroll
  for(int j = 0; j < 4; j++){
    al4[j] = al2[(tc << 2) + j];
    ar4[j] = ar2[(tc << 2) + j];
  }
  #pragma unroll
  for(int i = 0; i < 4; i++){
    int row = n0 + (tr << 2) + i;
    bool ok = row < NN;
    if(ok){
      float4 o = make_float4(acc[i][0], acc[i][1], acc[i][2], acc[i][3]);
      *(float4*)&ft2[(size_t)row * D2_ + (tc << 2)] = o;
    }
    float e1 = acc[i][0]*al4[0] + acc[i][1]*al4[1] + acc[i][2]*al4[2] + acc[i][3]*al4[3];
    float e2 = acc[i][0]*ar4[0] + acc[i][1]*ar4[1] + acc[i][2]*ar4[2] + acc[i][3]*ar4[3];
    #pragma unroll
    for(int off = 1; off < 32; off <<= 1){
      e1 += __shfl_xor(e1, off, 64);
      e2 += __shfl_xor(e2, off, 64);
    }
    if(tc == 0 && ok){ el[row] = e1; er[row] = e2; }
  }
}

// ---------------- layer-2 attn+agg, XCD-pinned per d-half ----------------
// half 0 -> xcd 0..3, half 1 -> xcd 4..7. Each block: 4 waves, 1 dn each.
__global__ __launch_bounds__(256) void l2_head(
    const int* __restrict__ rowptr, const int* __restrict__ ssrc,
    const float* __restrict__ el, const float* __restrict__ er,
    const float* __restrict__ ft2, const float* __restrict__ b2,
    float* __restrict__ h2v){
  int b = blockIdx.x;
  int xcd = b & 7, s = b >> 3;
  int half = xcd >> 2;
  int chunk = (xcd & 3) * 1250 + s;
  int wave = threadIdx.x >> 6, lane = threadIdx.x & 63;
  int eg = lane >> 3, dg = lane & 7;
  int dn = chunk * 4 + wave;
  int base = rowptr[dn], deg = rowptr[dn + 1] - base;
  float4 acc0 = make_float4(0.f,0.f,0.f,0.f);
  float4 acc1 = make_float4(0.f,0.f,0.f,0.f);
  int doff = half * 64 + (dg << 3);

  if(deg > 0 && deg <= 64){
    float er_d = er[dn];
    int sn_l = 0;
    float e_l = -INFINITY;
    if(lane < deg){
      sn_l = ssrc[base + lane];
      e_l = lrelu(el[sn_l] + er_d);
    }
    float mx = wmax64(e_l);
    float p = lane < deg ? expf(e_l - mx) : 0.f;
    float av = p / wsum64(p);
    for(int i = eg; i < deg; i += 8){
      int sn_i = __shfl(sn_l, i, 64);
      float a_i = __shfl(av, i, 64);
      const float* fp = &ft2[(size_t)sn_i * D2_ + doff];
      float4 f0 = *(const float4*)fp;
      float4 f1 = *(const float4*)(fp + 4);
      acc0.x += a_i * f0.x; acc0.y += a_i * f0.y;
      acc0.z += a_i * f0.z; acc0.w += a_i * f0.w;
      acc1.x += a_i * f1.x; acc1.y += a_i * f1.y;
      acc1.z += a_i * f1.z; acc1.w += a_i * f1.w;
    }
  } else if(deg > 64){
    float er_d = er[dn];
    float mx = -INFINITY;
    for(int i = lane; i < deg; i += 64)
      mx = fmaxf(mx, lrelu(el[ssrc[base + i]] + er_d));
    mx = wmax64(mx);
    float sm = 0.f;
    for(int i = lane; i < deg; i += 64)
      sm += expf(lrelu(el[ssrc[base + i]] + er_d) - mx);
    float inv = 1.f / wsum64(sm);
    for(int i = eg; i < deg; i += 8){
      int sn_i = ssrc[base + i];
      float a_i = expf(lrelu(el[sn_i] + er_d) - mx) * inv;
      const float* fp = &ft2[(size_t)sn_i * D2_ + doff];
      float4 f0 = *(const float4*)fp;
      float4 f1 = *(const float4*)(fp + 4);
      acc0.x += a_i * f0.x; acc0.y += a_i * f0.y;
      acc0.z += a_i * f0.z; acc0.w += a_i * f0.w;
      acc1.x += a_i * f1.x; acc1.y += a_i * f1.y;
      acc1.z += a_i * f1.z; acc1.w += a_i * f1.w;
    }
  }
  #pragma unroll
  for(int off = 8; off <= 32; off <<= 1){
    acc0.x += __shfl_xor(acc0.x, off, 64); acc0.y += __shfl_xor(acc0.y, off, 64);
    acc0.z += __shfl_xor(acc0.z, off, 64); acc0.w += __shfl_xor(acc0.w, off, 64);
    acc1.x += __shfl_xor(acc1.x, off, 64); acc1.y += __shfl_xor(acc1.y, off, 64);
    acc1.z += __shfl_xor(acc1.z, off, 64); acc1.w += __shfl_xor(acc1.w, off, 64);
  }
  if(eg == 0){
    const float* bp = &b2[doff];
    float4 o0, o1;
    o0.x = fmaxf(acc0.x + bp[0], 0.f);
    o0.y = fmaxf(acc0.y + bp[1], 0.f);
    o0.z = fmaxf(acc0.z + bp[2], 0.f);
    o0.w = fmaxf(acc0.w + bp[3], 0.f);
    o1.x = fmaxf(acc1.x + bp[4], 0.f);
    o1.y = fmaxf(acc1.y + bp[5], 0.f);
    o1.z = fmaxf(acc1.z + bp[6], 0.f);
    o1.w = fmaxf(acc1.w + bp[7], 0.f);
    float* op = &h2v[(size_t)dn * D2_ + doff];
    *(float4*)op = o0;
    *(float4*)(op + 4) = o1;
  }
}

// ---------------- per-graph max readout (graph_ids sorted) ----------------
__global__ __launch_bounds__(128) void graph_max(
    const float* __restrict__ h2v, const int* __restrict__ gid,
    int* __restrict__ rbuf){
  __shared__ int sb[2];
  int g = blockIdx.x, c = blockIdx.y, d = threadIdx.x;
  if(d < 2){
    int tgt = g + d;  // lower_bound(gid, tgt)
    int lo = 0, hi = NN;
    while(lo < hi){ int mid = (lo + hi) >> 1; if(gid[mid] < tgt) lo = mid + 1; else hi = mid; }
    sb[d] = lo;
  }
  __syncthreads();
  int gs = sb[0], ge = sb[1];
  int len = ge - gs;
  int cs = gs + (int)((long long)len * c / 4);
  int ce = gs + (int)((long long)len * (c + 1) / 4);
  float m0 = 0.f, m1 = 0.f, m2 = 0.f, m3 = 0.f;
  int n = cs;
  for(; n + 3 < ce; n += 4){
    m0 = fmaxf(m0, h2v[(size_t)(n + 0) * D2_ + d]);
    m1 = fmaxf(m1, h2v[(size_t)(n + 1) * D2_ + d]);
    m2 = fmaxf(m2, h2v[(size_t)(n + 2) * D2_ + d]);
    m3 = fmaxf(m3, h2v[(size_t)(n + 3) * D2_ + d]);
  }
  for(; n < ce; n++) m0 = fmaxf(m0, h2v[(size_t)n * D2_ + d]);
  float m = fmaxf(fmaxf(m0, m1), fmaxf(m2, m3));
  atomicMax(&rbuf[g * D2_ + d], __float_as_int(m));
}

__global__ void final_mlp(const float* __restrict__ r, const float* __restrict__ lw1,
                          const float* __restrict__ lb1, const float* __restrict__ lw2,
                          const float* __restrict__ lb2, float* __restrict__ out){
  __shared__ float rv[D2_];
  __shared__ float t[D2_];
  int g = blockIdx.x, j = threadIdx.x;
  rv[j] = r[g * D2_ + j];
  __syncthreads();
  float acc = lb1[j];
  #pragma unroll
  for(int k = 0; k < D2_; k++) acc += rv[k] * lw1[k * D2_ + j];
  acc = acc > 0.f ? acc : 0.f;
  t[j] = acc * lw2[j];
  __syncthreads();
  for(int off = 64; off > 0; off >>= 1){
    if(j < off) t[j] += t[j + off];
    __syncthreads();
  }
  if(j == 0){
    float v = t[0] + lb2[0];
    out[g] = v > 0.f ? v : 0.f;
  }
}

extern "C" void kernel_launch(void* const* d_in, const int* in_sizes, int n_in,
                              void* d_out, int out_size, void* d_ws, size_t ws_size,
                              hipStream_t stream) {
  const float* feat = (const float*)d_in[0];
  const int*   src  = (const int*)d_in[1];
  const int*   dst  = (const int*)d_in[2];
  const int*   gid  = (const int*)d_in[3];
  const float* W1   = (const float*)d_in[4];
  const float* al1  = (const float*)d_in[5];
  const float* ar1  = (const float*)d_in[6];
  const float* b1   = (const float*)d_in[7];
  const float* W2   = (const float*)d_in[8];
  const float* al2  = (const float*)d_in[9];
  const float* ar2  = (const float*)d_in[10];
  const float* b2   = (const float*)d_in[11];
  const float* lw1  = (const float*)d_in[12];
  const float* lb1  = (const float*)d_in[13];
  const float* lw2  = (const float*)d_in[14];
  const float* lb2  = (const float*)d_in[15];
  float* out = (float*)d_out;

  float* ws = (float*)d_ws;
  size_t o = 0;
  float* ft1  = ws + o; o += (size_t)NN * F1;     // 12.8M
  float* out1 = ws + o; o += (size_t)NN * F1;     // 12.8M (dead after sum_heads)
  float* h1v  = ws + o; o += (size_t)NN * D1_;
  float* el1  = ws + o; o += (size_t)NN * H1_;
  float* er1  = ws + o; o += (size_t)NN * H1_;
  float* el2  = ws + o; o += NN;
  float* er2  = ws + o; o += NN;
  float* rbuf = ws + o; o += (size_t)GG * D2_;
  int* hist   = (int*)(ws + o); o += NN;
  int* rowptr = (int*)(ws + o); o += NN + 1;
  int* cursor = (int*)(ws + o); o += NN;
  int* ssrc   = (int*)(ws + o); o += EE;
  // aliases into out1's space (out1 dead before gemm2 writes ft2)
  float* ft2  = out1;                     // 2.56M
  float* h2v  = out1 + (size_t)NN * D2_;  // 2.56M

  // ---- CSR build ----
  hipMemsetAsync(hist, 0, (size_t)NN * 4, stream);
  hist_k<<<cdiv(EE,256),256,0,stream>>>(dst, hist);
  scan_k<<<1,1024,0,stream>>>(hist, rowptr, cursor);
  scatter_k<<<cdiv(EE,256),256,0,stream>>>(src, dst, cursor, ssrc);

  // ---- layer 1 ----
  gemm1<<<dim3(H1_, cdiv(NN,64)), 256, 0, stream>>>(feat, W1, al1, ar1, ft1, el1, er1);
  l1_head<<<50000, 256, 0, stream>>>(rowptr, ssrc, el1, er1, ft1, b1, out1);
  sum_heads<<<cdiv((long long)NN*16,256),256,0,stream>>>(out1, h1v);

  // ---- layer 2 ----
  gemm2<<<cdiv(NN,32), 256, 0, stream>>>(h1v, W2, al2, ar2, ft2, el2, er2);
  l2_head<<<10000, 256, 0, stream>>>(rowptr, ssrc, el2, er2, ft2, b2, h2v);

  // ---- readout + MLP ----
  hipMemsetAsync(rbuf, 0, (size_t)GG * D2_ * 4, stream);
  graph_max<<<dim3(GG, 4), 128, 0, stream>>>(h2v, gid, (int*)rbuf);
  final_mlp<<<GG, D2_, 0, stream>>>(rbuf, lw1, lb1, lw2, lb2, out);
}

// Round 7
// 257.866 us; speedup vs baseline: 1.8223x; 1.0413x over previous
//
#include <hip/hip_runtime.h>
#include <hip/hip_fp16.h>

#define NN 20000
#define EE 320000
#define GG 50
#define IN_ 64
#define H1_ 10
#define D1_ 64
#define D2_ 128
#define F1 640   /* H1_*D1_ */
#define NEG 0.2f

static inline int cdiv(long long a, int b){ return (int)((a + b - 1) / b); }

__device__ inline float lrelu(float x){ return x > 0.f ? x : NEG * x; }
__device__ inline float wmax64(float x){
  #pragma unroll
  for(int off = 32; off > 0; off >>= 1) x = fmaxf(x, __shfl_xor(x, off, 64));
  return x;
}
__device__ inline float wsum64(float x){
  #pragma unroll
  for(int off = 32; off > 0; off >>= 1) x += __shfl_xor(x, off, 64);
  return x;
}

// ---------------- CSR build ----------------
__global__ void hist_k(const int* __restrict__ dst, int* __restrict__ hist){
  int e = blockIdx.x * blockDim.x + threadIdx.x;
  if(e < EE) atomicAdd(&hist[dst[e]], 1);
}

__global__ void scan_k(const int* __restrict__ hist, int* __restrict__ rowptr,
                       int* __restrict__ cursor){
  __shared__ int tot[1024];
  int t = threadIdx.x;
  int vals[20];
  int s = 0;
  #pragma unroll
  for(int i = 0; i < 20; i++){
    int idx = t * 20 + i;
    int v = idx < NN ? hist[idx] : 0;
    vals[i] = v; s += v;
  }
  tot[t] = s;
  __syncthreads();
  for(int off = 1; off < 1024; off <<= 1){
    int v = t >= off ? tot[t - off] : 0;
    __syncthreads();
    tot[t] += v;
    __syncthreads();
  }
  int run = tot[t] - s;
  #pragma unroll
  for(int i = 0; i < 20; i++){
    int idx = t * 20 + i;
    if(idx < NN){ rowptr[idx] = run; cursor[idx] = run; run += vals[i]; }
  }
  if(t == 1023) rowptr[NN] = tot[1023];
}

__global__ void scatter_k(const int* __restrict__ src, const int* __restrict__ dst,
                          int* __restrict__ cursor, int* __restrict__ ssrc){
  int e = blockIdx.x * blockDim.x + threadIdx.x;
  if(e >= EE) return;
  int pos = atomicAdd(&cursor[dst[e]], 1);
  ssrc[pos] = src[e];
}

// ---------------- GEMM1: ft1h[h][n][64] (fp16) = feat @ W1, fused el1/er1 ----------------
__global__ __launch_bounds__(256) void gemm1(
    const float* __restrict__ feat, const float* __restrict__ W1,
    const float* __restrict__ al1, const float* __restrict__ ar1,
    __half* __restrict__ ft1h, float* __restrict__ el, float* __restrict__ er){
  __shared__ float AsT[64][68];  // [k][r]
  __shared__ float Bs[64][68];   // [k][c]
  int h = blockIdx.x;
  int n0 = blockIdx.y * 64;
  int tid = threadIdx.x;
  #pragma unroll
  for(int l = 0; l < 4; l++){
    int idx = tid + l * 256;
    int r = idx >> 4, c4 = (idx & 15) << 2;
    float4 v = make_float4(0.f,0.f,0.f,0.f);
    if(n0 + r < NN) v = *(const float4*)&feat[(size_t)(n0 + r) * IN_ + c4];
    AsT[c4+0][r] = v.x; AsT[c4+1][r] = v.y; AsT[c4+2][r] = v.z; AsT[c4+3][r] = v.w;
    float4 w = *(const float4*)&W1[(size_t)(idx >> 4) * F1 + h * 64 + c4];
    *(float4*)&Bs[idx >> 4][c4] = w;
  }
  __syncthreads();
  int tr = tid >> 4, tc = tid & 15;
  float acc[4][4];
  #pragma unroll
  for(int i = 0; i < 4; i++)
    #pragma unroll
    for(int j = 0; j < 4; j++) acc[i][j] = 0.f;
  #pragma unroll 8
  for(int k = 0; k < 64; k++){
    float4 a4 = *(const float4*)&AsT[k][tr << 2];
    float4 b4 = *(const float4*)&Bs[k][tc << 2];
    float av[4] = {a4.x, a4.y, a4.z, a4.w};
    float bv[4] = {b4.x, b4.y, b4.z, b4.w};
    #pragma unroll
    for(int i = 0; i < 4; i++)
      #pragma unroll
      for(int j = 0; j < 4; j++) acc[i][j] += av[i] * bv[j];
  }
  float al4[4], ar4[4];
  #pragma unroll
  for(int j = 0; j < 4; j++){
    al4[j] = al1[h * 64 + (tc << 2) + j];
    ar4[j] = ar1[h * 64 + (tc << 2) + j];
  }
  #pragma unroll
  for(int i = 0; i < 4; i++){
    int row = n0 + (tr << 2) + i;
    bool ok = row < NN;
    if(ok){
      union { __half2 h2[2]; float2 f2; } u;
      u.h2[0] = __floats2half2_rn(acc[i][0], acc[i][1]);
      u.h2[1] = __floats2half2_rn(acc[i][2], acc[i][3]);
      *(float2*)&ft1h[((size_t)h * NN + row) * 64 + (tc << 2)] = u.f2;
    }
    float e1 = acc[i][0]*al4[0] + acc[i][1]*al4[1] + acc[i][2]*al4[2] + acc[i][3]*al4[3];
    float e2 = acc[i][0]*ar4[0] + acc[i][1]*ar4[1] + acc[i][2]*ar4[2] + acc[i][3]*ar4[3];
    #pragma unroll
    for(int off = 1; off < 16; off <<= 1){
      e1 += __shfl_xor(e1, off, 64);
      e2 += __shfl_xor(e2, off, 64);
    }
    if(tc == 0 && ok){ el[row * H1_ + h] = e1; er[row * H1_ + h] = e2; }
  }
}

// ---------------- layer-1 attn+agg, XCD-pinned per head, fp16 gather ----------------
__global__ __launch_bounds__(256) void l1_head(
    const int* __restrict__ rowptr, const int* __restrict__ ssrc,
    const float* __restrict__ el, const float* __restrict__ er,
    const __half* __restrict__ ft1h, const float* __restrict__ b1,
    float* __restrict__ out1){
  int b = blockIdx.x;
  int xcd = b & 7, slot = b >> 3;
  int h, chunk;
  if(slot < 5000){ h = xcd; chunk = slot; }
  else { int s = slot - 5000; h = 8 + (xcd >> 2); chunk = (xcd & 3) * 1250 + s; }
  int wave = threadIdx.x >> 6, lane = threadIdx.x & 63;
  int eg = lane >> 3, dg = lane & 7;
  int dn = chunk * 4 + wave;
  int base = rowptr[dn], deg = rowptr[dn + 1] - base;
  float4 acc0 = make_float4(0.f,0.f,0.f,0.f);
  float4 acc1 = make_float4(0.f,0.f,0.f,0.f);
  const __half* fbase = ft1h + (size_t)h * NN * 64 + (dg << 3);

  if(deg > 0 && deg <= 64){
    float er_h = er[dn * H1_ + h];
    int sn_l = 0;
    float e_l = -INFINITY;
    if(lane < deg){
      sn_l = ssrc[base + lane];
      e_l = lrelu(el[sn_l * H1_ + h] + er_h);
    }
    float mx = wmax64(e_l);
    float p = lane < deg ? expf(e_l - mx) : 0.f;
    float av = p / wsum64(p);
    for(int i = eg; i < deg; i += 8){
      int sn_i = __shfl(sn_l, i, 64);
      float a_i = __shfl(av, i, 64);
      float4 raw = *(const float4*)(fbase + (size_t)sn_i * 64);
      const __half2* hp = (const __half2*)&raw;
      float2 f0 = __half22float2(hp[0]);
      float2 f1 = __half22float2(hp[1]);
      float2 f2 = __half22float2(hp[2]);
      float2 f3 = __half22float2(hp[3]);
      acc0.x += a_i * f0.x; acc0.y += a_i * f0.y;
      acc0.z += a_i * f1.x; acc0.w += a_i * f1.y;
      acc1.x += a_i * f2.x; acc1.y += a_i * f2.y;
      acc1.z += a_i * f3.x; acc1.w += a_i * f3.y;
    }
  } else if(deg > 64){
    float er_h = er[dn * H1_ + h];
    float mx = -INFINITY;
    for(int i = lane; i < deg; i += 64)
      mx = fmaxf(mx, lrelu(el[ssrc[base + i] * H1_ + h] + er_h));
    mx = wmax64(mx);
    float sm = 0.f;
    for(int i = lane; i < deg; i += 64)
      sm += expf(lrelu(el[ssrc[base + i] * H1_ + h] + er_h) - mx);
    float inv = 1.f / wsum64(sm);
    for(int i = eg; i < deg; i += 8){
      int sn_i = ssrc[base + i];
      float a_i = expf(lrelu(el[sn_i * H1_ + h] + er_h) - mx) * inv;
      float4 raw = *(const float4*)(fbase + (size_t)sn_i * 64);
      const __half2* hp = (const __half2*)&raw;
      float2 f0 = __half22float2(hp[0]);
      float2 f1 = __half22float2(hp[1]);
      float2 f2 = __half22float2(hp[2]);
      float2 f3 = __half22float2(hp[3]);
      acc0.x += a_i * f0.x; acc0.y += a_i * f0.y;
      acc0.z += a_i * f1.x; acc0.w += a_i * f1.y;
      acc1.x += a_i * f2.x; acc1.y += a_i * f2.y;
      acc1.z += a_i * f3.x; acc1.w += a_i * f3.y;
    }
  }
  #pragma unroll
  for(int off = 8; off <= 32; off <<= 1){
    acc0.x += __shfl_xor(acc0.x, off, 64); acc0.y += __shfl_xor(acc0.y, off, 64);
    acc0.z += __shfl_xor(acc0.z, off, 64); acc0.w += __shfl_xor(acc0.w, off, 64);
    acc1.x += __shfl_xor(acc1.x, off, 64); acc1.y += __shfl_xor(acc1.y, off, 64);
    acc1.z += __shfl_xor(acc1.z, off, 64); acc1.w += __shfl_xor(acc1.w, off, 64);
  }
  if(eg == 0){
    int d = dg << 3;
    const float* bp = &b1[h * 64 + d];
    float4 o0, o1;
    o0.x = fmaxf(acc0.x + bp[0], 0.f);
    o0.y = fmaxf(acc0.y + bp[1], 0.f);
    o0.z = fmaxf(acc0.z + bp[2], 0.f);
    o0.w = fmaxf(acc0.w + bp[3], 0.f);
    o1.x = fmaxf(acc1.x + bp[4], 0.f);
    o1.y = fmaxf(acc1.y + bp[5], 0.f);
    o1.z = fmaxf(acc1.z + bp[6], 0.f);
    o1.w = fmaxf(acc1.w + bp[7], 0.f);
    float* op = &out1[(size_t)dn * F1 + h * 64 + d];
    *(float4*)op = o0;
    *(float4*)(op + 4) = o1;
  }
}

// h1v[n][d] = sum_h out1[n][h][d] (already relu'd+biased)
__global__ void sum_heads(const float* __restrict__ out1, float* __restrict__ h1v){
  int t = blockIdx.x * blockDim.x + threadIdx.x;
  if(t >= NN * 16) return;
  int n = t >> 4, d4 = (t & 15) << 2;
  float4 s = make_float4(0.f,0.f,0.f,0.f);
  #pragma unroll
  for(int h = 0; h < H1_; h++){
    float4 v = *(const float4*)&out1[(size_t)n * F1 + h * 64 + d4];
    s.x += v.x; s.y += v.y; s.z += v.z; s.w += v.w;
  }
  *(float4*)&h1v[n * D1_ + d4] = s;
}

// ---------------- GEMM2: ft2h[half][n][64] (fp16) = h1v @ W2, fused el2/er2 ----------------
__global__ __launch_bounds__(256) void gemm2(
    const float* __restrict__ h1v, const float* __restrict__ W2,
    const float* __restrict__ al2, const float* __restrict__ ar2,
    __half* __restrict__ ft2h, float* __restrict__ el, float* __restrict__ er){
  __shared__ float AsT[64][36];   // [k][r], r<32
  __shared__ float Bs[64][132];   // [k][c]
  int n0 = blockIdx.x * 32;
  int tid = threadIdx.x;
  #pragma unroll
  for(int l = 0; l < 2; l++){
    int idx = tid + l * 256;
    int r = idx >> 4, c4 = (idx & 15) << 2;
    float4 v = make_float4(0.f,0.f,0.f,0.f);
    if(n0 + r < NN) v = *(const float4*)&h1v[(size_t)(n0 + r) * D1_ + c4];
    AsT[c4+0][r] = v.x; AsT[c4+1][r] = v.y; AsT[c4+2][r] = v.z; AsT[c4+3][r] = v.w;
  }
  #pragma unroll
  for(int l = 0; l < 8; l++){
    int idx = tid + l * 256;
    int k = idx >> 5, c4 = (idx & 31) << 2;
    *(float4*)&Bs[k][c4] = *(const float4*)&W2[(size_t)k * D2_ + c4];
  }
  __syncthreads();
  int tr = tid >> 5, tc = tid & 31;
  float acc[4][4];
  #pragma unroll
  for(int i = 0; i < 4; i++)
    #pragma unroll
    for(int j = 0; j < 4; j++) acc[i][j] = 0.f;
  #pragma unroll 8
  for(int k = 0; k < 64; k++){
    float4 a4 = *(const float4*)&AsT[k][tr << 2];
    float4 b4 = *(const float4*)&Bs[k][tc << 2];
    float av[4] = {a4.x, a4.y, a4.z, a4.w};
    float bv[4] = {b4.x, b4.y, b4.z, b4.w};
    #pragma unroll
    for(int i = 0; i < 4; i++)
      #pragma unroll
      for(int j = 0; j < 4; j++) acc[i][j] += av[i] * bv[j];
  }
  float al4[4], ar4[4];
  #pragma unroll
  for(int j = 0; j < 4; j++){
    al4[j] = al2[(tc << 2) + j];
    ar4[j] = ar2[(tc << 2) + j];
  }
  int col = tc << 2;
  int half = col >> 6, c64 = col & 63;
  #pragma unroll
  for(int i = 0; i < 4; i++){
    int row = n0 + (tr << 2) + i;
    bool ok = row < NN;
    if(ok){
      union { __half2 h2[2]; float2 f2; } u;
      u.h2[0] = __floats2half2_rn(acc[i][0], acc[i][1]);
      u.h2[1] = __floats2half2_rn(acc[i][2], acc[i][3]);
      *(float2*)&ft2h[((size_t)half * NN + row) * 64 + c64] = u.f2;
    }
    float e1 = acc[i][0]*al4[0] + acc[i][1]*al4[1] + acc[i][2]*al4[2] + acc[i][3]*al4[3];
    float e2 = acc[i][0]*ar4[0] + acc[i][1]*ar4[1] + acc[i][2]*ar4[2] + acc[i][3]*ar4[3];
    #pragma unroll
    for(int off = 1; off < 32; off <<= 1){
      e1 += __shfl_xor(e1, off, 64);
      e2 += __shfl_xor(e2, off, 64);
    }
    if(tc == 0 && ok){ el[row] = e1; er[row] = e2; }
  }
}

// ---------------- layer-2 attn+agg, XCD-pinned per d-half, fp16 gather ----------------
__global__ __launch_bounds__(256) void l2_head(
    const int* __restrict__ rowptr, const int* __restrict__ ssrc,
    const float* __restrict__ el, const float* __restrict__ er,
    const __half* __restrict__ ft2h, const float* __restrict__ b2,
    float* __restrict__ h2v){
  int b = blockIdx.x;
  int xcd = b & 7, s = b >> 3;
  int half = xcd >> 2;
  int chunk = (xcd & 3) * 1250 + s;
  int wave = threadIdx.x >> 6, lane = threadIdx.x & 63;
  int eg = lane >> 3, dg = lane & 7;
  int dn = chunk * 4 + wave;
  int base = rowptr[dn], deg = rowptr[dn + 1] - base;
  float4 acc0 = make_float4(0.f,0.f,0.f,0.f);
  float4 acc1 = make_float4(0.f,0.f,0.f,0.f);
  const __half* fbase = ft2h + (size_t)half * NN * 64 + (dg << 3);

  if(deg > 0 && deg <= 64){
    float er_d = er[dn];
    int sn_l = 0;
    float e_l = -INFINITY;
    if(lane < deg){
      sn_l = ssrc[base + lane];
      e_l = lrelu(el[sn_l] + er_d);
    }
    float mx = wmax64(e_l);
    float p = lane < deg ? expf(e_l - mx) : 0.f;
    float av = p / wsum64(p);
    for(int i = eg; i < deg; i += 8){
      int sn_i = __shfl(sn_l, i, 64);
      float a_i = __shfl(av, i, 64);
      float4 raw = *(const float4*)(fbase + (size_t)sn_i * 64);
      const __half2* hp = (const __half2*)&raw;
      float2 f0 = __half22float2(hp[0]);
      float2 f1 = __half22float2(hp[1]);
      float2 f2 = __half22float2(hp[2]);
      float2 f3 = __half22float2(hp[3]);
      acc0.x += a_i * f0.x; acc0.y += a_i * f0.y;
      acc0.z += a_i * f1.x; acc0.w += a_i * f1.y;
      acc1.x += a_i * f2.x; acc1.y += a_i * f2.y;
      acc1.z += a_i * f3.x; acc1.w += a_i * f3.y;
    }
  } else if(deg > 64){
    float er_d = er[dn];
    float mx = -INFINITY;
    for(int i = lane; i < deg; i += 64)
      mx = fmaxf(mx, lrelu(el[ssrc[base + i]] + er_d));
    mx = wmax64(mx);
    float sm = 0.f;
    for(int i = lane; i < deg; i += 64)
      sm += expf(lrelu(el[ssrc[base + i]] + er_d) - mx);
    float inv = 1.f / wsum64(sm);
    for(int i = eg; i < deg; i += 8){
      int sn_i = ssrc[base + i];
      float a_i = expf(lrelu(el[sn_i] + er_d) - mx) * inv;
      float4 raw = *(const float4*)(fbase + (size_t)sn_i * 64);
      const __half2* hp = (const __half2*)&raw;
      float2 f0 = __half22float2(hp[0]);
      float2 f1 = __half22float2(hp[1]);
      float2 f2 = __half22float2(hp[2]);
      float2 f3 = __half22float2(hp[3]);
      acc0.x += a_i * f0.x; acc0.y += a_i * f0.y;
      acc0.z += a_i * f1.x; acc0.w += a_i * f1.y;
      acc1.x += a_i * f2.x; acc1.y += a_i * f2.y;
      acc1.z += a_i * f3.x; acc1.w += a_i * f3.y;
    }
  }
  #pragma unroll
  for(int off = 8; off <= 32; off <<= 1){
    acc0.x += __shfl_xor(acc0.x, off, 64); acc0.y += __shfl_xor(acc0.y, off, 64);
    acc0.z += __shfl_xor(acc0.z, off, 64); acc0.w += __shfl_xor(acc0.w, off, 64);
    acc1.x += __shfl_xor(acc1.x, off, 64); acc1.y += __shfl_xor(acc1.y, off, 64);
    acc1.z += __shfl_xor(acc1.z, off, 64); acc1.w += __shfl_xor(acc1.w, off, 64);
  }
  if(eg == 0){
    int doff = half * 64 + (dg << 3);
    const float* bp = &b2[doff];
    float4 o0, o1;
    o0.x = fmaxf(acc0.x + bp[0], 0.f);
    o0.y = fmaxf(acc0.y + bp[1], 0.f);
    o0.z = fmaxf(acc0.z + bp[2], 0.f);
    o0.w = fmaxf(acc0.w + bp[3], 0.f);
    o1.x = fmaxf(acc1.x + bp[4], 0.f);
    o1.y = fmaxf(acc1.y + bp[5], 0.f);
    o1.z = fmaxf(acc1.z + bp[6], 0.f);
    o1.w = fmaxf(acc1.w + bp[7], 0.f);
    float* op = &h2v[(size_t)dn * D2_ + doff];
    *(float4*)op = o0;
    *(float4*)(op + 4) = o1;
  }
}

// ---------------- per-graph max readout (graph_ids sorted) ----------------
__global__ __launch_bounds__(128) void graph_max(
    const float* __restrict__ h2v, const int* __restrict__ gid,
    int* __restrict__ rbuf){
  __shared__ int sb[2];
  int g = blockIdx.x, c = blockIdx.y, d = threadIdx.x;
  if(d < 2){
    int tgt = g + d;  // lower_bound(gid, tgt)
    int lo = 0, hi = NN;
    while(lo < hi){ int mid = (lo + hi) >> 1; if(gid[mid] < tgt) lo = mid + 1; else hi = mid; }
    sb[d] = lo;
  }
  __syncthreads();
  int gs = sb[0], ge = sb[1];
  int len = ge - gs;
  int cs = gs + (int)((long long)len * c / 4);
  int ce = gs + (int)((long long)len * (c + 1) / 4);
  float m0 = 0.f, m1 = 0.f, m2 = 0.f, m3 = 0.f;
  int n = cs;
  for(; n + 3 < ce; n += 4){
    m0 = fmaxf(m0, h2v[(size_t)(n + 0) * D2_ + d]);
    m1 = fmaxf(m1, h2v[(size_t)(n + 1) * D2_ + d]);
    m2 = fmaxf(m2, h2v[(size_t)(n + 2) * D2_ + d]);
    m3 = fmaxf(m3, h2v[(size_t)(n + 3) * D2_ + d]);
  }
  for(; n < ce; n++) m0 = fmaxf(m0, h2v[(size_t)n * D2_ + d]);
  float m = fmaxf(fmaxf(m0, m1), fmaxf(m2, m3));
  atomicMax(&rbuf[g * D2_ + d], __float_as_int(m));
}

__global__ void final_mlp(const float* __restrict__ r, const float* __restrict__ lw1,
                          const float* __restrict__ lb1, const float* __restrict__ lw2,
                          const float* __restrict__ lb2, float* __restrict__ out){
  __shared__ float rv[D2_];
  __shared__ float t[D2_];
  int g = blockIdx.x, j = threadIdx.x;
  rv[j] = r[g * D2_ + j];
  __syncthreads();
  float acc = lb1[j];
  #pragma unroll
  for(int k = 0; k < D2_; k++) acc += rv[k] * lw1[k * D2_ + j];
  acc = acc > 0.f ? acc : 0.f;
  t[j] = acc * lw2[j];
  __syncthreads();
  for(int off = 64; off > 0; off >>= 1){
    if(j < off) t[j] += t[j + off];
    __syncthreads();
  }
  if(j == 0){
    float v = t[0] + lb2[0];
    out[g] = v > 0.f ? v : 0.f;
  }
}

extern "C" void kernel_launch(void* const* d_in, const int* in_sizes, int n_in,
                              void* d_out, int out_size, void* d_ws, size_t ws_size,
                              hipStream_t stream) {
  const float* feat = (const float*)d_in[0];
  const int*   src  = (const int*)d_in[1];
  const int*   dst  = (const int*)d_in[2];
  const int*   gid  = (const int*)d_in[3];
  const float* W1   = (const float*)d_in[4];
  const float* al1  = (const float*)d_in[5];
  const float* ar1  = (const float*)d_in[6];
  const float* b1   = (const float*)d_in[7];
  const float* W2   = (const float*)d_in[8];
  const float* al2  = (const float*)d_in[9];
  const float* ar2  = (const float*)d_in[10];
  const float* b2   = (const float*)d_in[11];
  const float* lw1  = (const float*)d_in[12];
  const float* lb1  = (const float*)d_in[13];
  const float* lw2  = (const float*)d_in[14];
  const float* lb2  = (const float*)d_in[15];
  float* out = (float*)d_out;

  float* ws = (float*)d_ws;
  size_t o = 0;
  __half* ft1h = (__half*)(ws + o); o += (size_t)NN * F1 / 2;   // 25.6MB as halves
  float* out1 = ws + o; o += (size_t)NN * F1;                   // 51.2MB
  float* h1v  = ws + o; o += (size_t)NN * D1_;
  float* el1  = ws + o; o += (size_t)NN * H1_;
  float* er1  = ws + o; o += (size_t)NN * H1_;
  float* el2  = ws + o; o += NN;
  float* er2  = ws + o; o += NN;
  float* rbuf = ws + o; o += (size_t)GG * D2_;
  int* hist   = (int*)(ws + o); o += NN;
  int* rowptr = (int*)(ws + o); o += NN + 1;
  int* cursor = (int*)(ws + o); o += NN;
  int* ssrc   = (int*)(ws + o); o += EE;
  // aliases into out1's space (out1 dead before gemm2 writes ft2h)
  __half* ft2h = (__half*)out1;               // NN*128 halves = 1.28M floats
  float*  h2v  = out1 + (size_t)NN * 64;      // NN*128 floats

  // ---- CSR build ----
  hipMemsetAsync(hist, 0, (size_t)NN * 4, stream);
  hist_k<<<cdiv(EE,256),256,0,stream>>>(dst, hist);
  scan_k<<<1,1024,0,stream>>>(hist, rowptr, cursor);
  scatter_k<<<cdiv(EE,256),256,0,stream>>>(src, dst, cursor, ssrc);

  // ---- layer 1 ----
  gemm1<<<dim3(H1_, cdiv(NN,64)), 256, 0, stream>>>(feat, W1, al1, ar1, ft1h, el1, er1);
  l1_head<<<50000, 256, 0, stream>>>(rowptr, ssrc, el1, er1, ft1h, b1, out1);
  sum_heads<<<cdiv((long long)NN*16,256),256,0,stream>>>(out1, h1v);

  // ---- layer 2 ----
  gemm2<<<cdiv(NN,32), 256, 0, stream>>>(h1v, W2, al2, ar2, ft2h, el2, er2);
  l2_head<<<10000, 256, 0, stream>>>(rowptr, ssrc, el2, er2, ft2h, b2, h2v);

  // ---- readout + MLP ----
  hipMemsetAsync(rbuf, 0, (size_t)GG * D2_ * 4, stream);
  graph_max<<<dim3(GG, 4), 128, 0, stream>>>(h2v, gid, (int*)rbuf);
  final_mlp<<<GG, D2_, 0, stream>>>(rbuf, lw1, lb1, lw2, lb2, out);
}

// Round 8
// 248.166 us; speedup vs baseline: 1.8935x; 1.0391x over previous
//
#include <hip/hip_runtime.h>
#include <hip/hip_fp16.h>

#define NN 20000
#define EE 320000
#define GG 50
#define IN_ 64
#define H1_ 10
#define D1_ 64
#define D2_ 128
#define F1 640   /* H1_*D1_ */
#define NEG 0.2f

static inline int cdiv(long long a, int b){ return (int)((a + b - 1) / b); }

__device__ inline float lrelu(float x){ return x > 0.f ? x : NEG * x; }
__device__ inline float wsum64(float x){
  #pragma unroll
  for(int off = 32; off > 0; off >>= 1) x += __shfl_xor(x, off, 64);
  return x;
}

// ---------------- CSR build ----------------
__global__ void hist_k(const int* __restrict__ dst, int* __restrict__ hist){
  int e = blockIdx.x * blockDim.x + threadIdx.x;
  if(e < EE) atomicAdd(&hist[dst[e]], 1);
}

__global__ void scan_k(const int* __restrict__ hist, int* __restrict__ rowptr,
                       int* __restrict__ cursor){
  __shared__ int tot[1024];
  int t = threadIdx.x;
  int vals[20];
  int s = 0;
  #pragma unroll
  for(int i = 0; i < 20; i++){
    int idx = t * 20 + i;
    int v = idx < NN ? hist[idx] : 0;
    vals[i] = v; s += v;
  }
  tot[t] = s;
  __syncthreads();
  for(int off = 1; off < 1024; off <<= 1){
    int v = t >= off ? tot[t - off] : 0;
    __syncthreads();
    tot[t] += v;
    __syncthreads();
  }
  int run = tot[t] - s;
  #pragma unroll
  for(int i = 0; i < 20; i++){
    int idx = t * 20 + i;
    if(idx < NN){ rowptr[idx] = run; cursor[idx] = run; run += vals[i]; }
  }
  if(t == 1023) rowptr[NN] = tot[1023];
}

__global__ void scatter_k(const int* __restrict__ src, const int* __restrict__ dst,
                          int* __restrict__ cursor, int* __restrict__ ssrc){
  int e = blockIdx.x * blockDim.x + threadIdx.x;
  if(e >= EE) return;
  int pos = atomicAdd(&cursor[dst[e]], 1);
  ssrc[pos] = src[e];
}

// ---------------- GEMM1: ft1h[h][n][64] (fp16) = feat @ W1, fused el1/er1 ----------------
__global__ __launch_bounds__(256) void gemm1(
    const float* __restrict__ feat, const float* __restrict__ W1,
    const float* __restrict__ al1, const float* __restrict__ ar1,
    __half* __restrict__ ft1h, float* __restrict__ el, float* __restrict__ er){
  __shared__ float AsT[64][68];  // [k][r]
  __shared__ float Bs[64][68];   // [k][c]
  int h = blockIdx.x;
  int n0 = blockIdx.y * 64;
  int tid = threadIdx.x;
  #pragma unroll
  for(int l = 0; l < 4; l++){
    int idx = tid + l * 256;
    int r = idx >> 4, c4 = (idx & 15) << 2;
    float4 v = make_float4(0.f,0.f,0.f,0.f);
    if(n0 + r < NN) v = *(const float4*)&feat[(size_t)(n0 + r) * IN_ + c4];
    AsT[c4+0][r] = v.x; AsT[c4+1][r] = v.y; AsT[c4+2][r] = v.z; AsT[c4+3][r] = v.w;
    float4 w = *(const float4*)&W1[(size_t)(idx >> 4) * F1 + h * 64 + c4];
    *(float4*)&Bs[idx >> 4][c4] = w;
  }
  __syncthreads();
  int tr = tid >> 4, tc = tid & 15;
  float acc[4][4];
  #pragma unroll
  for(int i = 0; i < 4; i++)
    #pragma unroll
    for(int j = 0; j < 4; j++) acc[i][j] = 0.f;
  #pragma unroll 8
  for(int k = 0; k < 64; k++){
    float4 a4 = *(const float4*)&AsT[k][tr << 2];
    float4 b4 = *(const float4*)&Bs[k][tc << 2];
    float av[4] = {a4.x, a4.y, a4.z, a4.w};
    float bv[4] = {b4.x, b4.y, b4.z, b4.w};
    #pragma unroll
    for(int i = 0; i < 4; i++)
      #pragma unroll
      for(int j = 0; j < 4; j++) acc[i][j] += av[i] * bv[j];
  }
  float al4[4], ar4[4];
  #pragma unroll
  for(int j = 0; j < 4; j++){
    al4[j] = al1[h * 64 + (tc << 2) + j];
    ar4[j] = ar1[h * 64 + (tc << 2) + j];
  }
  #pragma unroll
  for(int i = 0; i < 4; i++){
    int row = n0 + (tr << 2) + i;
    bool ok = row < NN;
    if(ok){
      union { __half2 h2[2]; float2 f2; } u;
      u.h2[0] = __floats2half2_rn(acc[i][0], acc[i][1]);
      u.h2[1] = __floats2half2_rn(acc[i][2], acc[i][3]);
      *(float2*)&ft1h[((size_t)h * NN + row) * 64 + (tc << 2)] = u.f2;
    }
    float e1 = acc[i][0]*al4[0] + acc[i][1]*al4[1] + acc[i][2]*al4[2] + acc[i][3]*al4[3];
    float e2 = acc[i][0]*ar4[0] + acc[i][1]*ar4[1] + acc[i][2]*ar4[2] + acc[i][3]*ar4[3];
    #pragma unroll
    for(int off = 1; off < 16; off <<= 1){
      e1 += __shfl_xor(e1, off, 64);
      e2 += __shfl_xor(e2, off, 64);
    }
    if(tc == 0 && ok){ el[row * H1_ + h] = e1; er[row * H1_ + h] = e2; }
  }
}

// ---------------- layer-1 attn+agg, XCD-pinned per head, fp16 gather ----------------
// 4 waves/block, 1 dn each. Softmax edge=lane (no max-sub: scores are O(3)).
// Agg: 4 edge-groups x 16 lanes x 4 dims; (av, byteoff) via per-wave LDS pairs.
__global__ __launch_bounds__(256) void l1_head(
    const int* __restrict__ rowptr, const int* __restrict__ ssrc,
    const float* __restrict__ el, const float* __restrict__ er,
    const __half* __restrict__ ft1h, const float* __restrict__ b1,
    float* __restrict__ out1){
  __shared__ int2 pairs[4][64];
  int b = blockIdx.x;
  int xcd = b & 7, slot = b >> 3;
  int h, chunk;
  if(slot < 5000){ h = xcd; chunk = slot; }
  else { int s = slot - 5000; h = 8 + (xcd >> 2); chunk = (xcd & 3) * 1250 + s; }
  int wave = threadIdx.x >> 6, lane = threadIdx.x & 63;
  int eg = lane >> 4, dg = lane & 15;
  int dn = chunk * 4 + wave;
  int base = rowptr[dn], deg = rowptr[dn + 1] - base;
  float4 acc = make_float4(0.f,0.f,0.f,0.f);
  const char* fbase = (const char*)(ft1h + (size_t)h * NN * 64 + (dg << 2));
  int2* wp = pairs[wave];

  if(deg > 0 && deg <= 64){
    float er_h = er[dn * H1_ + h];
    int off = 0; float p = 0.f;
    if(lane < deg){
      int sn = ssrc[base + lane];
      off = sn << 7;  // sn * 64 halves * 2B
      p = __expf(lrelu(el[sn * H1_ + h] + er_h));
    }
    float inv = 1.f / wsum64(p);
    if(lane < deg) wp[lane] = make_int2(__float_as_int(p * inv), off);
    for(int i = eg; i < deg; i += 4){
      int2 pr = wp[i];
      float a_i = __int_as_float(pr.x);
      float2 raw = *(const float2*)(fbase + pr.y);
      const __half2* hp = (const __half2*)&raw;
      float2 f0 = __half22float2(hp[0]);
      float2 f1 = __half22float2(hp[1]);
      acc.x += a_i * f0.x; acc.y += a_i * f0.y;
      acc.z += a_i * f1.x; acc.w += a_i * f1.y;
    }
  } else if(deg > 64){
    float er_h = er[dn * H1_ + h];
    float sm = 0.f;
    for(int i = lane; i < deg; i += 64)
      sm += __expf(lrelu(el[ssrc[base + i] * H1_ + h] + er_h));
    float inv = 1.f / wsum64(sm);
    for(int c = 0; c < deg; c += 64){
      int m = deg - c; if(m > 64) m = 64;
      if(lane < m){
        int sn = ssrc[base + c + lane];
        wp[lane] = make_int2(
            __float_as_int(__expf(lrelu(el[sn * H1_ + h] + er_h)) * inv), sn << 7);
      }
      for(int i = eg; i < m; i += 4){
        int2 pr = wp[i];
        float a_i = __int_as_float(pr.x);
        float2 raw = *(const float2*)(fbase + pr.y);
        const __half2* hp = (const __half2*)&raw;
        float2 f0 = __half22float2(hp[0]);
        float2 f1 = __half22float2(hp[1]);
        acc.x += a_i * f0.x; acc.y += a_i * f0.y;
        acc.z += a_i * f1.x; acc.w += a_i * f1.y;
      }
    }
  }
  #pragma unroll
  for(int off = 16; off <= 32; off <<= 1){
    acc.x += __shfl_xor(acc.x, off, 64);
    acc.y += __shfl_xor(acc.y, off, 64);
    acc.z += __shfl_xor(acc.z, off, 64);
    acc.w += __shfl_xor(acc.w, off, 64);
  }
  if(eg == 0){
    int d = dg << 2;
    const float* bp = &b1[h * 64 + d];
    float4 o;
    o.x = fmaxf(acc.x + bp[0], 0.f);
    o.y = fmaxf(acc.y + bp[1], 0.f);
    o.z = fmaxf(acc.z + bp[2], 0.f);
    o.w = fmaxf(acc.w + bp[3], 0.f);
    *(float4*)&out1[(size_t)dn * F1 + h * 64 + d] = o;
  }
}

// ---------------- GEMM2: A = head-sum(out1) on the fly; fp16 out + el2/er2 ----------------
__global__ __launch_bounds__(256) void gemm2(
    const float* __restrict__ out1, const float* __restrict__ W2,
    const float* __restrict__ al2, const float* __restrict__ ar2,
    __half* __restrict__ ft2h, float* __restrict__ el, float* __restrict__ er){
  __shared__ float AsT[64][36];   // [k][r], r<32
  __shared__ float Bs[64][132];   // [k][c]
  int n0 = blockIdx.x * 32;
  int tid = threadIdx.x;
  #pragma unroll
  for(int l = 0; l < 2; l++){
    int idx = tid + l * 256;
    int r = idx >> 4, c4 = (idx & 15) << 2;
    float4 sv = make_float4(0.f,0.f,0.f,0.f);
    if(n0 + r < NN){
      const float* rp = &out1[(size_t)(n0 + r) * F1 + c4];
      #pragma unroll
      for(int hh = 0; hh < H1_; hh++){
        float4 v = *(const float4*)(rp + hh * 64);
        sv.x += v.x; sv.y += v.y; sv.z += v.z; sv.w += v.w;
      }
    }
    AsT[c4+0][r] = sv.x; AsT[c4+1][r] = sv.y; AsT[c4+2][r] = sv.z; AsT[c4+3][r] = sv.w;
  }
  #pragma unroll
  for(int l = 0; l < 8; l++){
    int idx = tid + l * 256;
    int k = idx >> 5, c4 = (idx & 31) << 2;
    *(float4*)&Bs[k][c4] = *(const float4*)&W2[(size_t)k * D2_ + c4];
  }
  __syncthreads();
  int tr = tid >> 5, tc = tid & 31;
  float acc[4][4];
  #pragma unroll
  for(int i = 0; i < 4; i++)
    #pragma unroll
    for(int j = 0; j < 4; j++) acc[i][j] = 0.f;
  #pragma unroll 8
  for(int k = 0; k < 64; k++){
    float4 a4 = *(const float4*)&AsT[k][tr << 2];
    float4 b4 = *(const float4*)&Bs[k][tc << 2];
    float av[4] = {a4.x, a4.y, a4.z, a4.w};
    float bv[4] = {b4.x, b4.y, b4.z, b4.w};
    #pragma unroll
    for(int i = 0; i < 4; i++)
      #pragma unroll
      for(int j = 0; j < 4; j++) acc[i][j] += av[i] * bv[j];
  }
  float al4[4], ar4[4];
  #pragma unroll
  for(int j = 0; j < 4; j++){
    al4[j] = al2[(tc << 2) + j];
    ar4[j] = ar2[(tc << 2) + j];
  }
  int col = tc << 2;
  int half = col >> 6, c64 = col & 63;
  #pragma unroll
  for(int i = 0; i < 4; i++){
    int row = n0 + (tr << 2) + i;
    bool ok = row < NN;
    if(ok){
      union { __half2 h2[2]; float2 f2; } u;
      u.h2[0] = __floats2half2_rn(acc[i][0], acc[i][1]);
      u.h2[1] = __floats2half2_rn(acc[i][2], acc[i][3]);
      *(float2*)&ft2h[((size_t)half * NN + row) * 64 + c64] = u.f2;
    }
    float e1 = acc[i][0]*al4[0] + acc[i][1]*al4[1] + acc[i][2]*al4[2] + acc[i][3]*al4[3];
    float e2 = acc[i][0]*ar4[0] + acc[i][1]*ar4[1] + acc[i][2]*ar4[2] + acc[i][3]*ar4[3];
    #pragma unroll
    for(int off = 1; off < 32; off <<= 1){
      e1 += __shfl_xor(e1, off, 64);
      e2 += __shfl_xor(e2, off, 64);
    }
    if(tc == 0 && ok){ el[row] = e1; er[row] = e2; }
  }
}

// ---------------- layer-2 attn+agg, XCD-pinned per d-half, fp16 gather ----------------
__global__ __launch_bounds__(256) void l2_head(
    const int* __restrict__ rowptr, const int* __restrict__ ssrc,
    const float* __restrict__ el, const float* __restrict__ er,
    const __half* __restrict__ ft2h, const float* __restrict__ b2,
    float* __restrict__ h2v){
  __shared__ int2 pairs[4][64];
  int b = blockIdx.x;
  int xcd = b & 7, s = b >> 3;
  int half = xcd >> 2;
  int chunk = (xcd & 3) * 1250 + s;
  int wave = threadIdx.x >> 6, lane = threadIdx.x & 63;
  int eg = lane >> 4, dg = lane & 15;
  int dn = chunk * 4 + wave;
  int base = rowptr[dn], deg = rowptr[dn + 1] - base;
  float4 acc = make_float4(0.f,0.f,0.f,0.f);
  const char* fbase = (const char*)(ft2h + (size_t)half * NN * 64 + (dg << 2));
  int2* wp = pairs[wave];

  if(deg > 0 && deg <= 64){
    float er_d = er[dn];
    int off = 0; float p = 0.f;
    if(lane < deg){
      int sn = ssrc[base + lane];
      off = sn << 7;
      p = __expf(lrelu(el[sn] + er_d));
    }
    float inv = 1.f / wsum64(p);
    if(lane < deg) wp[lane] = make_int2(__float_as_int(p * inv), off);
    for(int i = eg; i < deg; i += 4){
      int2 pr = wp[i];
      float a_i = __int_as_float(pr.x);
      float2 raw = *(const float2*)(fbase + pr.y);
      const __half2* hp = (const __half2*)&raw;
      float2 f0 = __half22float2(hp[0]);
      float2 f1 = __half22float2(hp[1]);
      acc.x += a_i * f0.x; acc.y += a_i * f0.y;
      acc.z += a_i * f1.x; acc.w += a_i * f1.y;
    }
  } else if(deg > 64){
    float er_d = er[dn];
    float sm = 0.f;
    for(int i = lane; i < deg; i += 64)
      sm += __expf(lrelu(el[ssrc[base + i]] + er_d));
    float inv = 1.f / wsum64(sm);
    for(int c = 0; c < deg; c += 64){
      int m = deg - c; if(m > 64) m = 64;
      if(lane < m){
        int sn = ssrc[base + c + lane];
        wp[lane] = make_int2(__float_as_int(__expf(lrelu(el[sn] + er_d)) * inv), sn << 7);
      }
      for(int i = eg; i < m; i += 4){
        int2 pr = wp[i];
        float a_i = __int_as_float(pr.x);
        float2 raw = *(const float2*)(fbase + pr.y);
        const __half2* hp = (const __half2*)&raw;
        float2 f0 = __half22float2(hp[0]);
        float2 f1 = __half22float2(hp[1]);
        acc.x += a_i * f0.x; acc.y += a_i * f0.y;
        acc.z += a_i * f1.x; acc.w += a_i * f1.y;
      }
    }
  }
  #pragma unroll
  for(int off = 16; off <= 32; off <<= 1){
    acc.x += __shfl_xor(acc.x, off, 64);
    acc.y += __shfl_xor(acc.y, off, 64);
    acc.z += __shfl_xor(acc.z, off, 64);
    acc.w += __shfl_xor(acc.w, off, 64);
  }
  if(eg == 0){
    int doff = half * 64 + (dg << 2);
    const float* bp = &b2[doff];
    float4 o;
    o.x = fmaxf(acc.x + bp[0], 0.f);
    o.y = fmaxf(acc.y + bp[1], 0.f);
    o.z = fmaxf(acc.z + bp[2], 0.f);
    o.w = fmaxf(acc.w + bp[3], 0.f);
    *(float4*)&h2v[(size_t)dn * D2_ + doff] = o;
  }
}

// ---------------- per-graph max readout (graph_ids sorted) ----------------
__global__ __launch_bounds__(128) void graph_max(
    const float* __restrict__ h2v, const int* __restrict__ gid,
    int* __restrict__ rbuf){
  __shared__ int sb[2];
  int g = blockIdx.x, c = blockIdx.y, d = threadIdx.x;
  if(d < 2){
    int tgt = g + d;  // lower_bound(gid, tgt)
    int lo = 0, hi = NN;
    while(lo < hi){ int mid = (lo + hi) >> 1; if(gid[mid] < tgt) lo = mid + 1; else hi = mid; }
    sb[d] = lo;
  }
  __syncthreads();
  int gs = sb[0], ge = sb[1];
  int len = ge - gs;
  int cs = gs + (int)((long long)len * c / 4);
  int ce = gs + (int)((long long)len * (c + 1) / 4);
  float m0 = 0.f, m1 = 0.f, m2 = 0.f, m3 = 0.f;
  int n = cs;
  for(; n + 3 < ce; n += 4){
    m0 = fmaxf(m0, h2v[(size_t)(n + 0) * D2_ + d]);
    m1 = fmaxf(m1, h2v[(size_t)(n + 1) * D2_ + d]);
    m2 = fmaxf(m2, h2v[(size_t)(n + 2) * D2_ + d]);
    m3 = fmaxf(m3, h2v[(size_t)(n + 3) * D2_ + d]);
  }
  for(; n < ce; n++) m0 = fmaxf(m0, h2v[(size_t)n * D2_ + d]);
  float m = fmaxf(fmaxf(m0, m1), fmaxf(m2, m3));
  atomicMax(&rbuf[g * D2_ + d], __float_as_int(m));
}

__global__ void final_mlp(const float* __restrict__ r, const float* __restrict__ lw1,
                          const float* __restrict__ lb1, const float* __restrict__ lw2,
                          const float* __restrict__ lb2, float* __restrict__ out){
  __shared__ float rv[D2_];
  __shared__ float t[D2_];
  int g = blockIdx.x, j = threadIdx.x;
  rv[j] = r[g * D2_ + j];
  __syncthreads();
  float acc = lb1[j];
  #pragma unroll
  for(int k = 0; k < D2_; k++) acc += rv[k] * lw1[k * D2_ + j];
  acc = acc > 0.f ? acc : 0.f;
  t[j] = acc * lw2[j];
  __syncthreads();
  for(int off = 64; off > 0; off >>= 1){
    if(j < off) t[j] += t[j + off];
    __syncthreads();
  }
  if(j == 0){
    float v = t[0] + lb2[0];
    out[g] = v > 0.f ? v : 0.f;
  }
}

extern "C" void kernel_launch(void* const* d_in, const int* in_sizes, int n_in,
                              void* d_out, int out_size, void* d_ws, size_t ws_size,
                              hipStream_t stream) {
  const float* feat = (const float*)d_in[0];
  const int*   src  = (const int*)d_in[1];
  const int*   dst  = (const int*)d_in[2];
  const int*   gid  = (const int*)d_in[3];
  const float* W1   = (const float*)d_in[4];
  const float* al1  = (const float*)d_in[5];
  const float* ar1  = (const float*)d_in[6];
  const float* b1   = (const float*)d_in[7];
  const float* W2   = (const float*)d_in[8];
  const float* al2  = (const float*)d_in[9];
  const float* ar2  = (const float*)d_in[10];
  const float* b2   = (const float*)d_in[11];
  const float* lw1  = (const float*)d_in[12];
  const float* lb1  = (const float*)d_in[13];
  const float* lw2  = (const float*)d_in[14];
  const float* lb2  = (const float*)d_in[15];
  float* out = (float*)d_out;

  float* ws = (float*)d_ws;
  size_t o = 0;
  __half* ft1h = (__half*)(ws + o); o += (size_t)NN * F1 / 2;   // 25.6MB
  float* out1 = ws + o; o += (size_t)NN * F1;                   // 51.2MB
  __half* ft2h = (__half*)(ws + o); o += (size_t)NN * D2_ / 2;  // 5.12MB
  float* h2v  = ws + o; o += (size_t)NN * D2_;                  // 10.24MB
  float* el1  = ws + o; o += (size_t)NN * H1_;
  float* er1  = ws + o; o += (size_t)NN * H1_;
  float* el2  = ws + o; o += NN;
  float* er2  = ws + o; o += NN;
  float* rbuf = ws + o; o += (size_t)GG * D2_;
  int* hist   = (int*)(ws + o); o += NN;
  int* rowptr = (int*)(ws + o); o += NN + 1;
  int* cursor = (int*)(ws + o); o += NN;
  int* ssrc   = (int*)(ws + o); o += EE;

  // ---- CSR build ----
  hipMemsetAsync(hist, 0, (size_t)NN * 4, stream);
  hist_k<<<cdiv(EE,256),256,0,stream>>>(dst, hist);
  scan_k<<<1,1024,0,stream>>>(hist, rowptr, cursor);
  scatter_k<<<cdiv(EE,256),256,0,stream>>>(src, dst, cursor, ssrc);

  // ---- layer 1 ----
  gemm1<<<dim3(H1_, cdiv(NN,64)), 256, 0, stream>>>(feat, W1, al1, ar1, ft1h, el1, er1);
  l1_head<<<50000, 256, 0, stream>>>(rowptr, ssrc, el1, er1, ft1h, b1, out1);

  // ---- layer 2 (head-sum fused into gemm2 A-load) ----
  gemm2<<<cdiv(NN,32), 256, 0, stream>>>(out1, W2, al2, ar2, ft2h, el2, er2);
  l2_head<<<10000, 256, 0, stream>>>(rowptr, ssrc, el2, er2, ft2h, b2, h2v);

  // ---- readout + MLP ----
  hipMemsetAsync(rbuf, 0, (size_t)GG * D2_ * 4, stream);
  graph_max<<<dim3(GG, 4), 128, 0, stream>>>(h2v, gid, (int*)rbuf);
  final_mlp<<<GG, D2_, 0, stream>>>(rbuf, lw1, lb1, lw2, lb2, out);
}

// Round 9
// 207.664 us; speedup vs baseline: 2.2628x; 1.1950x over previous
//
#include <hip/hip_runtime.h>
#include <hip/hip_fp16.h>

#define NN 20000
#define EE 320000
#define GG 50
#define IN_ 64
#define H1_ 10
#define D1_ 64
#define D2_ 128
#define F1 640   /* H1_*D1_ */
#define NEG 0.2f

static inline int cdiv(long long a, int b){ return (int)((a + b - 1) / b); }

__device__ inline float lrelu(float x){ return x > 0.f ? x : NEG * x; }
__device__ inline float wsum64(float x){
  #pragma unroll
  for(int off = 32; off > 0; off >>= 1) x += __shfl_xor(x, off, 64);
  return x;
}

// ---------------- CSR build ----------------
__global__ void hist_k(const int* __restrict__ dst, int* __restrict__ hist){
  int e = blockIdx.x * blockDim.x + threadIdx.x;
  if(e < EE) atomicAdd(&hist[dst[e]], 1);
}

// block-local exclusive scan; bsum[b] = block total
__global__ __launch_bounds__(256) void scan1(
    const int* __restrict__ hist, int* __restrict__ rowptr, int* __restrict__ bsum){
  __shared__ int tmp[256];
  int b = blockIdx.x, t = threadIdx.x;
  int idx = b * 256 + t;
  int v = idx < NN ? hist[idx] : 0;
  tmp[t] = v;
  __syncthreads();
  for(int off = 1; off < 256; off <<= 1){
    int x = t >= off ? tmp[t - off] : 0;
    __syncthreads();
    tmp[t] += x;
    __syncthreads();
  }
  if(idx < NN) rowptr[idx] = tmp[t] - v;
  if(t == 255) bsum[b] = tmp[255];
}

// add block prefix; write cursor; rowptr[NN] = EE (known)
__global__ __launch_bounds__(256) void scan2(
    int* __restrict__ rowptr, const int* __restrict__ bsum, int* __restrict__ cursor){
  __shared__ int pre;
  int b = blockIdx.x, t = threadIdx.x;
  if(t == 0){
    int s = 0;
    for(int i = 0; i < b; i++) s += bsum[i];
    pre = s;
  }
  __syncthreads();
  int idx = b * 256 + t;
  if(idx < NN){
    int r = rowptr[idx] + pre;
    rowptr[idx] = r;
    cursor[idx] = r;
  }
  if(idx == 0) rowptr[NN] = EE;
}

__global__ void scatter_k(const int* __restrict__ src, const int* __restrict__ dst,
                          int* __restrict__ cursor, int* __restrict__ ssrc){
  int e = blockIdx.x * blockDim.x + threadIdx.x;
  if(e >= EE) return;
  int pos = atomicAdd(&cursor[dst[e]], 1);
  ssrc[pos] = src[e];
}

// ---------------- GEMM1: ft1h[h][n][64] fp16; elT/erT[h][n] ----------------
__global__ __launch_bounds__(256) void gemm1(
    const float* __restrict__ feat, const float* __restrict__ W1,
    const float* __restrict__ al1, const float* __restrict__ ar1,
    __half* __restrict__ ft1h, float* __restrict__ elT, float* __restrict__ erT){
  __shared__ float AsT[64][68];  // [k][r]
  __shared__ float Bs[64][68];   // [k][c]
  int h = blockIdx.x;
  int n0 = blockIdx.y * 64;
  int tid = threadIdx.x;
  #pragma unroll
  for(int l = 0; l < 4; l++){
    int idx = tid + l * 256;
    int r = idx >> 4, c4 = (idx & 15) << 2;
    float4 v = make_float4(0.f,0.f,0.f,0.f);
    if(n0 + r < NN) v = *(const float4*)&feat[(size_t)(n0 + r) * IN_ + c4];
    AsT[c4+0][r] = v.x; AsT[c4+1][r] = v.y; AsT[c4+2][r] = v.z; AsT[c4+3][r] = v.w;
    float4 w = *(const float4*)&W1[(size_t)(idx >> 4) * F1 + h * 64 + c4];
    *(float4*)&Bs[idx >> 4][c4] = w;
  }
  __syncthreads();
  int tr = tid >> 4, tc = tid & 15;
  float acc[4][4];
  #pragma unroll
  for(int i = 0; i < 4; i++)
    #pragma unroll
    for(int j = 0; j < 4; j++) acc[i][j] = 0.f;
  #pragma unroll 8
  for(int k = 0; k < 64; k++){
    float4 a4 = *(const float4*)&AsT[k][tr << 2];
    float4 b4 = *(const float4*)&Bs[k][tc << 2];
    float av[4] = {a4.x, a4.y, a4.z, a4.w};
    float bv[4] = {b4.x, b4.y, b4.z, b4.w};
    #pragma unroll
    for(int i = 0; i < 4; i++)
      #pragma unroll
      for(int j = 0; j < 4; j++) acc[i][j] += av[i] * bv[j];
  }
  float al4[4], ar4[4];
  #pragma unroll
  for(int j = 0; j < 4; j++){
    al4[j] = al1[h * 64 + (tc << 2) + j];
    ar4[j] = ar1[h * 64 + (tc << 2) + j];
  }
  #pragma unroll
  for(int i = 0; i < 4; i++){
    int row = n0 + (tr << 2) + i;
    bool ok = row < NN;
    if(ok){
      union { __half2 h2[2]; float2 f2; } u;
      u.h2[0] = __floats2half2_rn(acc[i][0], acc[i][1]);
      u.h2[1] = __floats2half2_rn(acc[i][2], acc[i][3]);
      *(float2*)&ft1h[((size_t)h * NN + row) * 64 + (tc << 2)] = u.f2;
    }
    float e1 = acc[i][0]*al4[0] + acc[i][1]*al4[1] + acc[i][2]*al4[2] + acc[i][3]*al4[3];
    float e2 = acc[i][0]*ar4[0] + acc[i][1]*ar4[1] + acc[i][2]*ar4[2] + acc[i][3]*ar4[3];
    #pragma unroll
    for(int off = 1; off < 16; off <<= 1){
      e1 += __shfl_xor(e1, off, 64);
      e2 += __shfl_xor(e2, off, 64);
    }
    if(tc == 0 && ok){
      elT[(size_t)h * NN + row] = e1;
      erT[(size_t)h * NN + row] = e2;
    }
  }
}

// ---------------- layer-1 attn+agg, XCD-pinned per head, fp16 gather ----------------
// 4 waves/block, 1 dn each; elT slice (80KB) ~L1-resident; 2x unrolled gather.
__global__ __launch_bounds__(256) void l1_head(
    const int* __restrict__ rowptr, const int* __restrict__ ssrc,
    const float* __restrict__ elT, const float* __restrict__ erT,
    const __half* __restrict__ ft1h, const float* __restrict__ b1,
    __half* __restrict__ out1h){
  __shared__ int2 pairs[4][64];
  int b = blockIdx.x;
  int xcd = b & 7, slot = b >> 3;
  int h, chunk;
  if(slot < 5000){ h = xcd; chunk = slot; }
  else { int s = slot - 5000; h = 8 + (xcd >> 2); chunk = (xcd & 3) * 1250 + s; }
  int wave = threadIdx.x >> 6, lane = threadIdx.x & 63;
  int eg = lane >> 4, dg = lane & 15;
  int dn = chunk * 4 + wave;
  int base = rowptr[dn], deg = rowptr[dn + 1] - base;
  float4 acc = make_float4(0.f,0.f,0.f,0.f);
  float4 acc2 = make_float4(0.f,0.f,0.f,0.f);
  const char* fbase = (const char*)(ft1h + (size_t)h * NN * 64 + (dg << 2));
  const float* elh = elT + (size_t)h * NN;
  int2* wp = pairs[wave];

  if(deg > 0 && deg <= 64){
    float er_h = erT[(size_t)h * NN + dn];
    int off = 0; float p = 0.f;
    if(lane < deg){
      int sn = ssrc[base + lane];
      off = sn << 7;  // sn * 64 halves * 2B
      p = __expf(lrelu(elh[sn] + er_h));
    }
    float inv = 1.f / wsum64(p);
    if(lane < deg) wp[lane] = make_int2(__float_as_int(p * inv), off);
    int i = eg;
    for(; i + 4 < deg; i += 8){
      int2 p1 = wp[i], p2 = wp[i + 4];
      float2 r1 = *(const float2*)(fbase + p1.y);
      float2 r2 = *(const float2*)(fbase + p2.y);
      float a1 = __int_as_float(p1.x), a2 = __int_as_float(p2.x);
      const __half2* h1p = (const __half2*)&r1;
      const __half2* h2p = (const __half2*)&r2;
      float2 f0 = __half22float2(h1p[0]), f1 = __half22float2(h1p[1]);
      float2 g0 = __half22float2(h2p[0]), g1 = __half22float2(h2p[1]);
      acc.x  += a1 * f0.x; acc.y  += a1 * f0.y; acc.z  += a1 * f1.x; acc.w  += a1 * f1.y;
      acc2.x += a2 * g0.x; acc2.y += a2 * g0.y; acc2.z += a2 * g1.x; acc2.w += a2 * g1.y;
    }
    if(i < deg){
      int2 p1 = wp[i];
      float2 r1 = *(const float2*)(fbase + p1.y);
      float a1 = __int_as_float(p1.x);
      const __half2* h1p = (const __half2*)&r1;
      float2 f0 = __half22float2(h1p[0]), f1 = __half22float2(h1p[1]);
      acc.x += a1 * f0.x; acc.y += a1 * f0.y; acc.z += a1 * f1.x; acc.w += a1 * f1.y;
    }
  } else if(deg > 64){
    float er_h = erT[(size_t)h * NN + dn];
    float sm = 0.f;
    for(int i = lane; i < deg; i += 64)
      sm += __expf(lrelu(elh[ssrc[base + i]] + er_h));
    float inv = 1.f / wsum64(sm);
    for(int c = 0; c < deg; c += 64){
      int m = deg - c; if(m > 64) m = 64;
      if(lane < m){
        int sn = ssrc[base + c + lane];
        wp[lane] = make_int2(__float_as_int(__expf(lrelu(elh[sn] + er_h)) * inv), sn << 7);
      }
      for(int i = eg; i < m; i += 4){
        int2 pr = wp[i];
        float a_i = __int_as_float(pr.x);
        float2 raw = *(const float2*)(fbase + pr.y);
        const __half2* hp = (const __half2*)&raw;
        float2 f0 = __half22float2(hp[0]);
        float2 f1 = __half22float2(hp[1]);
        acc.x += a_i * f0.x; acc.y += a_i * f0.y;
        acc.z += a_i * f1.x; acc.w += a_i * f1.y;
      }
    }
  }
  acc.x += acc2.x; acc.y += acc2.y; acc.z += acc2.z; acc.w += acc2.w;
  #pragma unroll
  for(int off = 16; off <= 32; off <<= 1){
    acc.x += __shfl_xor(acc.x, off, 64);
    acc.y += __shfl_xor(acc.y, off, 64);
    acc.z += __shfl_xor(acc.z, off, 64);
    acc.w += __shfl_xor(acc.w, off, 64);
  }
  if(eg == 0){
    int d = dg << 2;
    const float* bp = &b1[h * 64 + d];
    union { __half2 h2[2]; float2 f2; } u;
    u.h2[0] = __floats2half2_rn(fmaxf(acc.x + bp[0], 0.f), fmaxf(acc.y + bp[1], 0.f));
    u.h2[1] = __floats2half2_rn(fmaxf(acc.z + bp[2], 0.f), fmaxf(acc.w + bp[3], 0.f));
    *(float2*)&out1h[(size_t)dn * F1 + h * 64 + d] = u.f2;
  }
}

// ---------------- GEMM2: A = head-sum(out1h fp16) on the fly; fp16 out + el2/er2 ----------------
__global__ __launch_bounds__(256) void gemm2(
    const __half* __restrict__ out1h, const float* __restrict__ W2,
    const float* __restrict__ al2, const float* __restrict__ ar2,
    __half* __restrict__ ft2h, float* __restrict__ el, float* __restrict__ er){
  __shared__ float AsT[64][36];   // [k][r], r<32
  __shared__ float Bs[64][132];   // [k][c]
  int n0 = blockIdx.x * 32;
  int tid = threadIdx.x;
  #pragma unroll
  for(int l = 0; l < 2; l++){
    int idx = tid + l * 256;
    int r = idx >> 4, c4 = (idx & 15) << 2;
    float4 sv = make_float4(0.f,0.f,0.f,0.f);
    if(n0 + r < NN){
      const __half* rp = &out1h[(size_t)(n0 + r) * F1 + c4];
      #pragma unroll
      for(int hh = 0; hh < H1_; hh++){
        float2 raw = *(const float2*)(rp + hh * 64);
        const __half2* hp = (const __half2*)&raw;
        float2 f0 = __half22float2(hp[0]);
        float2 f1 = __half22float2(hp[1]);
        sv.x += f0.x; sv.y += f0.y; sv.z += f1.x; sv.w += f1.y;
      }
    }
    AsT[c4+0][r] = sv.x; AsT[c4+1][r] = sv.y; AsT[c4+2][r] = sv.z; AsT[c4+3][r] = sv.w;
  }
  #pragma unroll
  for(int l = 0; l < 8; l++){
    int idx = tid + l * 256;
    int k = idx >> 5, c4 = (idx & 31) << 2;
    *(float4*)&Bs[k][c4] = *(const float4*)&W2[(size_t)k * D2_ + c4];
  }
  __syncthreads();
  int tr = tid >> 5, tc = tid & 31;
  float acc[4][4];
  #pragma unroll
  for(int i = 0; i < 4; i++)
    #pragma unroll
    for(int j = 0; j < 4; j++) acc[i][j] = 0.f;
  #pragma unroll 8
  for(int k = 0; k < 64; k++){
    float4 a4 = *(const float4*)&AsT[k][tr << 2];
    float4 b4 = *(const float4*)&Bs[k][tc << 2];
    float av[4] = {a4.x, a4.y, a4.z, a4.w};
    float bv[4] = {b4.x, b4.y, b4.z, b4.w};
    #pragma unroll
    for(int i = 0; i < 4; i++)
      #pragma unroll
      for(int j = 0; j < 4; j++) acc[i][j] += av[i] * bv[j];
  }
  float al4[4], ar4[4];
  #pragma unroll
  for(int j = 0; j < 4; j++){
    al4[j] = al2[(tc << 2) + j];
    ar4[j] = ar2[(tc << 2) + j];
  }
  int col = tc << 2;
  int half = col >> 6, c64 = col & 63;
  #pragma unroll
  for(int i = 0; i < 4; i++){
    int row = n0 + (tr << 2) + i;
    bool ok = row < NN;
    if(ok){
      union { __half2 h2[2]; float2 f2; } u;
      u.h2[0] = __floats2half2_rn(acc[i][0], acc[i][1]);
      u.h2[1] = __floats2half2_rn(acc[i][2], acc[i][3]);
      *(float2*)&ft2h[((size_t)half * NN + row) * 64 + c64] = u.f2;
    }
    float e1 = acc[i][0]*al4[0] + acc[i][1]*al4[1] + acc[i][2]*al4[2] + acc[i][3]*al4[3];
    float e2 = acc[i][0]*ar4[0] + acc[i][1]*ar4[1] + acc[i][2]*ar4[2] + acc[i][3]*ar4[3];
    #pragma unroll
    for(int off = 1; off < 32; off <<= 1){
      e1 += __shfl_xor(e1, off, 64);
      e2 += __shfl_xor(e2, off, 64);
    }
    if(tc == 0 && ok){ el[row] = e1; er[row] = e2; }
  }
}

// ---------------- layer-2 attn+agg, XCD-pinned per d-half, fp16 gather ----------------
__global__ __launch_bounds__(256) void l2_head(
    const int* __restrict__ rowptr, const int* __restrict__ ssrc,
    const float* __restrict__ el, const float* __restrict__ er,
    const __half* __restrict__ ft2h, const float* __restrict__ b2,
    float* __restrict__ h2v){
  __shared__ int2 pairs[4][64];
  int b = blockIdx.x;
  int xcd = b & 7, s = b >> 3;
  int half = xcd >> 2;
  int chunk = (xcd & 3) * 1250 + s;
  int wave = threadIdx.x >> 6, lane = threadIdx.x & 63;
  int eg = lane >> 4, dg = lane & 15;
  int dn = chunk * 4 + wave;
  int base = rowptr[dn], deg = rowptr[dn + 1] - base;
  float4 acc = make_float4(0.f,0.f,0.f,0.f);
  float4 acc2 = make_float4(0.f,0.f,0.f,0.f);
  const char* fbase = (const char*)(ft2h + (size_t)half * NN * 64 + (dg << 2));
  int2* wp = pairs[wave];

  if(deg > 0 && deg <= 64){
    float er_d = er[dn];
    int off = 0; float p = 0.f;
    if(lane < deg){
      int sn = ssrc[base + lane];
      off = sn << 7;
      p = __expf(lrelu(el[sn] + er_d));
    }
    float inv = 1.f / wsum64(p);
    if(lane < deg) wp[lane] = make_int2(__float_as_int(p * inv), off);
    int i = eg;
    for(; i + 4 < deg; i += 8){
      int2 p1 = wp[i], p2 = wp[i + 4];
      float2 r1 = *(const float2*)(fbase + p1.y);
      float2 r2 = *(const float2*)(fbase + p2.y);
      float a1 = __int_as_float(p1.x), a2 = __int_as_float(p2.x);
      const __half2* h1p = (const __half2*)&r1;
      const __half2* h2p = (const __half2*)&r2;
      float2 f0 = __half22float2(h1p[0]), f1 = __half22float2(h1p[1]);
      float2 g0 = __half22float2(h2p[0]), g1 = __half22float2(h2p[1]);
      acc.x  += a1 * f0.x; acc.y  += a1 * f0.y; acc.z  += a1 * f1.x; acc.w  += a1 * f1.y;
      acc2.x += a2 * g0.x; acc2.y += a2 * g0.y; acc2.z += a2 * g1.x; acc2.w += a2 * g1.y;
    }
    if(i < deg){
      int2 p1 = wp[i];
      float2 r1 = *(const float2*)(fbase + p1.y);
      float a1 = __int_as_float(p1.x);
      const __half2* h1p = (const __half2*)&r1;
      float2 f0 = __half22float2(h1p[0]), f1 = __half22float2(h1p[1]);
      acc.x += a1 * f0.x; acc.y += a1 * f0.y; acc.z += a1 * f1.x; acc.w += a1 * f1.y;
    }
  } else if(deg > 64){
    float er_d = er[dn];
    float sm = 0.f;
    for(int i = lane; i < deg; i += 64)
      sm += __expf(lrelu(el[ssrc[base + i]] + er_d));
    float inv = 1.f / wsum64(sm);
    for(int c = 0; c < deg; c += 64){
      int m = deg - c; if(m > 64) m = 64;
      if(lane < m){
        int sn = ssrc[base + c + lane];
        wp[lane] = make_int2(__float_as_int(__expf(lrelu(el[sn] + er_d)) * inv), sn << 7);
      }
      for(int i = eg; i < m; i += 4){
        int2 pr = wp[i];
        float a_i = __int_as_float(pr.x);
        float2 raw = *(const float2*)(fbase + pr.y);
        const __half2* hp = (const __half2*)&raw;
        float2 f0 = __half22float2(hp[0]);
        float2 f1 = __half22float2(hp[1]);
        acc.x += a_i * f0.x; acc.y += a_i * f0.y;
        acc.z += a_i * f1.x; acc.w += a_i * f1.y;
      }
    }
  }
  acc.x += acc2.x; acc.y += acc2.y; acc.z += acc2.z; acc.w += acc2.w;
  #pragma unroll
  for(int off = 16; off <= 32; off <<= 1){
    acc.x += __shfl_xor(acc.x, off, 64);
    acc.y += __shfl_xor(acc.y, off, 64);
    acc.z += __shfl_xor(acc.z, off, 64);
    acc.w += __shfl_xor(acc.w, off, 64);
  }
  if(eg == 0){
    int doff = half * 64 + (dg << 2);
    const float* bp = &b2[doff];
    float4 o;
    o.x = fmaxf(acc.x + bp[0], 0.f);
    o.y = fmaxf(acc.y + bp[1], 0.f);
    o.z = fmaxf(acc.z + bp[2], 0.f);
    o.w = fmaxf(acc.w + bp[3], 0.f);
    *(float4*)&h2v[(size_t)dn * D2_ + doff] = o;
  }
}

// ---------------- per-graph max readout (graph_ids sorted) ----------------
__global__ __launch_bounds__(128) void graph_max(
    const float* __restrict__ h2v, const int* __restrict__ gid,
    int* __restrict__ rbuf){
  __shared__ int sb[2];
  int g = blockIdx.x, c = blockIdx.y, d = threadIdx.x;
  if(d < 2){
    int tgt = g + d;  // lower_bound(gid, tgt)
    int lo = 0, hi = NN;
    while(lo < hi){ int mid = (lo + hi) >> 1; if(gid[mid] < tgt) lo = mid + 1; else hi = mid; }
    sb[d] = lo;
  }
  __syncthreads();
  int gs = sb[0], ge = sb[1];
  int len = ge - gs;
  int cs = gs + (int)((long long)len * c / 4);
  int ce = gs + (int)((long long)len * (c + 1) / 4);
  float m0 = 0.f, m1 = 0.f, m2 = 0.f, m3 = 0.f;
  int n = cs;
  for(; n + 3 < ce; n += 4){
    m0 = fmaxf(m0, h2v[(size_t)(n + 0) * D2_ + d]);
    m1 = fmaxf(m1, h2v[(size_t)(n + 1) * D2_ + d]);
    m2 = fmaxf(m2, h2v[(size_t)(n + 2) * D2_ + d]);
    m3 = fmaxf(m3, h2v[(size_t)(n + 3) * D2_ + d]);
  }
  for(; n < ce; n++) m0 = fmaxf(m0, h2v[(size_t)n * D2_ + d]);
  float m = fmaxf(fmaxf(m0, m1), fmaxf(m2, m3));
  atomicMax(&rbuf[g * D2_ + d], __float_as_int(m));
}

__global__ void final_mlp(const float* __restrict__ r, const float* __restrict__ lw1,
                          const float* __restrict__ lb1, const float* __restrict__ lw2,
                          const float* __restrict__ lb2, float* __restrict__ out){
  __shared__ float rv[D2_];
  __shared__ float t[D2_];
  int g = blockIdx.x, j = threadIdx.x;
  rv[j] = r[g * D2_ + j];
  __syncthreads();
  float acc = lb1[j];
  #pragma unroll
  for(int k = 0; k < D2_; k++) acc += rv[k] * lw1[k * D2_ + j];
  acc = acc > 0.f ? acc : 0.f;
  t[j] = acc * lw2[j];
  __syncthreads();
  for(int off = 64; off > 0; off >>= 1){
    if(j < off) t[j] += t[j + off];
    __syncthreads();
  }
  if(j == 0){
    float v = t[0] + lb2[0];
    out[g] = v > 0.f ? v : 0.f;
  }
}

extern "C" void kernel_launch(void* const* d_in, const int* in_sizes, int n_in,
                              void* d_out, int out_size, void* d_ws, size_t ws_size,
                              hipStream_t stream) {
  const float* feat = (const float*)d_in[0];
  const int*   src  = (const int*)d_in[1];
  const int*   dst  = (const int*)d_in[2];
  const int*   gid  = (const int*)d_in[3];
  const float* W1   = (const float*)d_in[4];
  const float* al1  = (const float*)d_in[5];
  const float* ar1  = (const float*)d_in[6];
  const float* b1   = (const float*)d_in[7];
  const float* W2   = (const float*)d_in[8];
  const float* al2  = (const float*)d_in[9];
  const float* ar2  = (const float*)d_in[10];
  const float* b2   = (const float*)d_in[11];
  const float* lw1  = (const float*)d_in[12];
  const float* lb1  = (const float*)d_in[13];
  const float* lw2  = (const float*)d_in[14];
  const float* lb2  = (const float*)d_in[15];
  float* out = (float*)d_out;

  float* ws = (float*)d_ws;
  size_t o = 0;
  __half* ft1h = (__half*)(ws + o); o += (size_t)NN * F1 / 2;   // 25.6MB
  __half* out1h = (__half*)(ws + o); o += (size_t)NN * F1 / 2;  // 25.6MB
  __half* ft2h = (__half*)(ws + o); o += (size_t)NN * D2_ / 2;  // 5.12MB
  float* h2v  = ws + o; o += (size_t)NN * D2_;                  // 10.24MB
  float* el1  = ws + o; o += (size_t)NN * H1_;
  float* er1  = ws + o; o += (size_t)NN * H1_;
  float* el2  = ws + o; o += NN;
  float* er2  = ws + o; o += NN;
  float* rbuf = ws + o; o += (size_t)GG * D2_;
  int* hist   = (int*)(ws + o); o += NN;
  int* rowptr = (int*)(ws + o); o += NN + 1;
  int* cursor = (int*)(ws + o); o += NN;
  int* bsum   = (int*)(ws + o); o += 128;
  int* ssrc   = (int*)(ws + o); o += EE;

  // ---- CSR build ----
  hipMemsetAsync(hist, 0, (size_t)NN * 4, stream);
  hist_k<<<cdiv(EE,256),256,0,stream>>>(dst, hist);
  scan1<<<cdiv(NN,256),256,0,stream>>>(hist, rowptr, bsum);
  scan2<<<cdiv(NN,256),256,0,stream>>>(rowptr, bsum, cursor);
  scatter_k<<<cdiv(EE,256),256,0,stream>>>(src, dst, cursor, ssrc);

  // ---- layer 1 ----
  gemm1<<<dim3(H1_, cdiv(NN,64)), 256, 0, stream>>>(feat, W1, al1, ar1, ft1h, el1, er1);
  l1_head<<<50000, 256, 0, stream>>>(rowptr, ssrc, el1, er1, ft1h, b1, out1h);

  // ---- layer 2 (head-sum fused into gemm2 A-load) ----
  gemm2<<<cdiv(NN,32), 256, 0, stream>>>(out1h, W2, al2, ar2, ft2h, el2, er2);
  l2_head<<<10000, 256, 0, stream>>>(rowptr, ssrc, el2, er2, ft2h, b2, h2v);

  // ---- readout + MLP ----
  hipMemsetAsync(rbuf, 0, (size_t)GG * D2_ * 4, stream);
  graph_max<<<dim3(GG, 4), 128, 0, stream>>>(h2v, gid, (int*)rbuf);
  final_mlp<<<GG, D2_, 0, stream>>>(rbuf, lw1, lb1, lw2, lb2, out);
}

// Round 10
// 206.218 us; speedup vs baseline: 2.2787x; 1.0070x over previous
//
#include <hip/hip_runtime.h>
#include <hip/hip_fp16.h>

#define NN 20000
#define EE 320000
#define GG 50
#define IN_ 64
#define H1_ 10
#define D1_ 64
#define D2_ 128
#define F1 640   /* H1_*D1_ */
#define NEG 0.2f

static inline int cdiv(long long a, int b){ return (int)((a + b - 1) / b); }

__device__ inline float lrelu(float x){ return x > 0.f ? x : NEG * x; }
__device__ inline float wsum64(float x){
  #pragma unroll
  for(int off = 32; off > 0; off >>= 1) x += __shfl_xor(x, off, 64);
  return x;
}

// acc += (f16 lo/hi of packed) * a   — fp32 accumulate, single VOP3P op
__device__ inline void fma_mix_lo(float& acc, float packed, float a){
  asm("v_fma_mix_f32 %0, %1, %2, %0 op_sel_hi:[1,0,0]"
      : "+v"(acc) : "v"(packed), "v"(a));
}
__device__ inline void fma_mix_hi(float& acc, float packed, float a){
  asm("v_fma_mix_f32 %0, %1, %2, %0 op_sel:[1,0,0] op_sel_hi:[1,0,0]"
      : "+v"(acc) : "v"(packed), "v"(a));
}

// ---------------- CSR build ----------------
__global__ void hist_k(const int* __restrict__ dst, int* __restrict__ hist){
  int e = blockIdx.x * blockDim.x + threadIdx.x;
  if(e < EE) atomicAdd(&hist[dst[e]], 1);
}

__global__ __launch_bounds__(256) void scan1(
    const int* __restrict__ hist, int* __restrict__ rowptr, int* __restrict__ bsum){
  __shared__ int tmp[256];
  int b = blockIdx.x, t = threadIdx.x;
  int idx = b * 256 + t;
  int v = idx < NN ? hist[idx] : 0;
  tmp[t] = v;
  __syncthreads();
  for(int off = 1; off < 256; off <<= 1){
    int x = t >= off ? tmp[t - off] : 0;
    __syncthreads();
    tmp[t] += x;
    __syncthreads();
  }
  if(idx < NN) rowptr[idx] = tmp[t] - v;
  if(t == 255) bsum[b] = tmp[255];
}

__global__ __launch_bounds__(256) void scan2(
    int* __restrict__ rowptr, const int* __restrict__ bsum, int* __restrict__ cursor){
  __shared__ int pre;
  int b = blockIdx.x, t = threadIdx.x;
  if(t == 0){
    int s = 0;
    for(int i = 0; i < b; i++) s += bsum[i];
    pre = s;
  }
  __syncthreads();
  int idx = b * 256 + t;
  if(idx < NN){
    int r = rowptr[idx] + pre;
    rowptr[idx] = r;
    cursor[idx] = r;
  }
  if(idx == 0) rowptr[NN] = EE;
}

__global__ void scatter_k(const int* __restrict__ src, const int* __restrict__ dst,
                          int* __restrict__ cursor, int* __restrict__ ssrc){
  int e = blockIdx.x * blockDim.x + threadIdx.x;
  if(e >= EE) return;
  int pos = atomicAdd(&cursor[dst[e]], 1);
  ssrc[pos] = src[e];
}

// ---------------- GEMM1: ft1h[h][n][64] fp16; elT/erT[h][n] ----------------
__global__ __launch_bounds__(256) void gemm1(
    const float* __restrict__ feat, const float* __restrict__ W1,
    const float* __restrict__ al1, const float* __restrict__ ar1,
    __half* __restrict__ ft1h, float* __restrict__ elT, float* __restrict__ erT){
  __shared__ float AsT[64][68];  // [k][r]
  __shared__ float Bs[64][68];   // [k][c]
  int h = blockIdx.x;
  int n0 = blockIdx.y * 64;
  int tid = threadIdx.x;
  #pragma unroll
  for(int l = 0; l < 4; l++){
    int idx = tid + l * 256;
    int r = idx >> 4, c4 = (idx & 15) << 2;
    float4 v = make_float4(0.f,0.f,0.f,0.f);
    if(n0 + r < NN) v = *(const float4*)&feat[(size_t)(n0 + r) * IN_ + c4];
    AsT[c4+0][r] = v.x; AsT[c4+1][r] = v.y; AsT[c4+2][r] = v.z; AsT[c4+3][r] = v.w;
    float4 w = *(const float4*)&W1[(size_t)(idx >> 4) * F1 + h * 64 + c4];
    *(float4*)&Bs[idx >> 4][c4] = w;
  }
  __syncthreads();
  int tr = tid >> 4, tc = tid & 15;
  float acc[4][4];
  #pragma unroll
  for(int i = 0; i < 4; i++)
    #pragma unroll
    for(int j = 0; j < 4; j++) acc[i][j] = 0.f;
  #pragma unroll 8
  for(int k = 0; k < 64; k++){
    float4 a4 = *(const float4*)&AsT[k][tr << 2];
    float4 b4 = *(const float4*)&Bs[k][tc << 2];
    float av[4] = {a4.x, a4.y, a4.z, a4.w};
    float bv[4] = {b4.x, b4.y, b4.z, b4.w};
    #pragma unroll
    for(int i = 0; i < 4; i++)
      #pragma unroll
      for(int j = 0; j < 4; j++) acc[i][j] += av[i] * bv[j];
  }
  float al4[4], ar4[4];
  #pragma unroll
  for(int j = 0; j < 4; j++){
    al4[j] = al1[h * 64 + (tc << 2) + j];
    ar4[j] = ar1[h * 64 + (tc << 2) + j];
  }
  #pragma unroll
  for(int i = 0; i < 4; i++){
    int row = n0 + (tr << 2) + i;
    bool ok = row < NN;
    if(ok){
      union { __half2 h2[2]; float2 f2; } u;
      u.h2[0] = __floats2half2_rn(acc[i][0], acc[i][1]);
      u.h2[1] = __floats2half2_rn(acc[i][2], acc[i][3]);
      *(float2*)&ft1h[((size_t)h * NN + row) * 64 + (tc << 2)] = u.f2;
    }
    float e1 = acc[i][0]*al4[0] + acc[i][1]*al4[1] + acc[i][2]*al4[2] + acc[i][3]*al4[3];
    float e2 = acc[i][0]*ar4[0] + acc[i][1]*ar4[1] + acc[i][2]*ar4[2] + acc[i][3]*ar4[3];
    #pragma unroll
    for(int off = 1; off < 16; off <<= 1){
      e1 += __shfl_xor(e1, off, 64);
      e2 += __shfl_xor(e2, off, 64);
    }
    if(tc == 0 && ok){
      elT[(size_t)h * NN + row] = e1;
      erT[(size_t)h * NN + row] = e2;
    }
  }
}

// ---------------- layer-1 attn+agg, XCD-pinned per head, fma_mix gather ----------------
__global__ __launch_bounds__(256) void l1_head(
    const int* __restrict__ rowptr, const int* __restrict__ ssrc,
    const float* __restrict__ elT, const float* __restrict__ erT,
    const __half* __restrict__ ft1h, const float* __restrict__ b1,
    __half* __restrict__ out1h){
  __shared__ int2 pairs[4][64];
  int b = blockIdx.x;
  int xcd = b & 7, slot = b >> 3;
  int h, chunk;
  if(slot < 5000){ h = xcd; chunk = slot; }
  else { int s = slot - 5000; h = 8 + (xcd >> 2); chunk = (xcd & 3) * 1250 + s; }
  int wave = threadIdx.x >> 6, lane = threadIdx.x & 63;
  int eg = lane >> 4, dg = lane & 15;
  int dn = chunk * 4 + wave;
  int base = rowptr[dn], deg = rowptr[dn + 1] - base;
  float4 acc = make_float4(0.f,0.f,0.f,0.f);
  float4 acc2 = make_float4(0.f,0.f,0.f,0.f);
  const char* fbase = (const char*)(ft1h + (size_t)h * NN * 64 + (dg << 2));
  const float* elh = elT + (size_t)h * NN;
  int2* wp = pairs[wave];

  if(deg > 0 && deg <= 64){
    float er_h = erT[(size_t)h * NN + dn];
    int off = 0; float p = 0.f;
    if(lane < deg){
      int sn = ssrc[base + lane];
      off = sn << 7;  // sn * 64 halves * 2B
      p = __expf(lrelu(elh[sn] + er_h));
    }
    float inv = 1.f / wsum64(p);
    if(lane < deg) wp[lane] = make_int2(__float_as_int(p * inv), off);
    int i = eg;
    for(; i + 4 < deg; i += 8){
      int2 p1 = wp[i], p2 = wp[i + 4];
      float2 r1 = *(const float2*)(fbase + p1.y);
      float2 r2 = *(const float2*)(fbase + p2.y);
      float a1 = __int_as_float(p1.x), a2 = __int_as_float(p2.x);
      fma_mix_lo(acc.x, r1.x, a1);  fma_mix_hi(acc.y, r1.x, a1);
      fma_mix_lo(acc.z, r1.y, a1);  fma_mix_hi(acc.w, r1.y, a1);
      fma_mix_lo(acc2.x, r2.x, a2); fma_mix_hi(acc2.y, r2.x, a2);
      fma_mix_lo(acc2.z, r2.y, a2); fma_mix_hi(acc2.w, r2.y, a2);
    }
    if(i < deg){
      int2 p1 = wp[i];
      float2 r1 = *(const float2*)(fbase + p1.y);
      float a1 = __int_as_float(p1.x);
      fma_mix_lo(acc.x, r1.x, a1); fma_mix_hi(acc.y, r1.x, a1);
      fma_mix_lo(acc.z, r1.y, a1); fma_mix_hi(acc.w, r1.y, a1);
    }
  } else if(deg > 64){
    float er_h = erT[(size_t)h * NN + dn];
    float sm = 0.f;
    for(int i = lane; i < deg; i += 64)
      sm += __expf(lrelu(elh[ssrc[base + i]] + er_h));
    float inv = 1.f / wsum64(sm);
    for(int c = 0; c < deg; c += 64){
      int m = deg - c; if(m > 64) m = 64;
      if(lane < m){
        int sn = ssrc[base + c + lane];
        wp[lane] = make_int2(__float_as_int(__expf(lrelu(elh[sn] + er_h)) * inv), sn << 7);
      }
      for(int i = eg; i < m; i += 4){
        int2 pr = wp[i];
        float a_i = __int_as_float(pr.x);
        float2 raw = *(const float2*)(fbase + pr.y);
        fma_mix_lo(acc.x, raw.x, a_i); fma_mix_hi(acc.y, raw.x, a_i);
        fma_mix_lo(acc.z, raw.y, a_i); fma_mix_hi(acc.w, raw.y, a_i);
      }
    }
  }
  acc.x += acc2.x; acc.y += acc2.y; acc.z += acc2.z; acc.w += acc2.w;
  #pragma unroll
  for(int off = 16; off <= 32; off <<= 1){
    acc.x += __shfl_xor(acc.x, off, 64);
    acc.y += __shfl_xor(acc.y, off, 64);
    acc.z += __shfl_xor(acc.z, off, 64);
    acc.w += __shfl_xor(acc.w, off, 64);
  }
  if(eg == 0){
    int d = dg << 2;
    const float* bp = &b1[h * 64 + d];
    union { __half2 h2[2]; float2 f2; } u;
    u.h2[0] = __floats2half2_rn(fmaxf(acc.x + bp[0], 0.f), fmaxf(acc.y + bp[1], 0.f));
    u.h2[1] = __floats2half2_rn(fmaxf(acc.z + bp[2], 0.f), fmaxf(acc.w + bp[3], 0.f));
    *(float2*)&out1h[(size_t)dn * F1 + h * 64 + d] = u.f2;
  }
}

// ---------------- GEMM2: A = head-sum(out1h fp16) on the fly; fp16 out + el2/er2 ----------------
__global__ __launch_bounds__(256) void gemm2(
    const __half* __restrict__ out1h, const float* __restrict__ W2,
    const float* __restrict__ al2, const float* __restrict__ ar2,
    __half* __restrict__ ft2h, float* __restrict__ el, float* __restrict__ er){
  __shared__ float AsT[64][36];   // [k][r], r<32
  __shared__ float Bs[64][132];   // [k][c]
  int n0 = blockIdx.x * 32;
  int tid = threadIdx.x;
  #pragma unroll
  for(int l = 0; l < 2; l++){
    int idx = tid + l * 256;
    int r = idx >> 4, c4 = (idx & 15) << 2;
    float4 sv = make_float4(0.f,0.f,0.f,0.f);
    if(n0 + r < NN){
      const __half* rp = &out1h[(size_t)(n0 + r) * F1 + c4];
      #pragma unroll
      for(int hh = 0; hh < H1_; hh++){
        float2 raw = *(const float2*)(rp + hh * 64);
        const __half2* hp = (const __half2*)&raw;
        float2 f0 = __half22float2(hp[0]);
        float2 f1 = __half22float2(hp[1]);
        sv.x += f0.x; sv.y += f0.y; sv.z += f1.x; sv.w += f1.y;
      }
    }
    AsT[c4+0][r] = sv.x; AsT[c4+1][r] = sv.y; AsT[c4+2][r] = sv.z; AsT[c4+3][r] = sv.w;
  }
  #pragma unroll
  for(int l = 0; l < 8; l++){
    int idx = tid + l * 256;
    int k = idx >> 5, c4 = (idx & 31) << 2;
    *(float4*)&Bs[k][c4] = *(const float4*)&W2[(size_t)k * D2_ + c4];
  }
  __syncthreads();
  int tr = tid >> 5, tc = tid & 31;
  float acc[4][4];
  #pragma unroll
  for(int i = 0; i < 4; i++)
    #pragma unroll
    for(int j = 0; j < 4; j++) acc[i][j] = 0.f;
  #pragma unroll 8
  for(int k = 0; k < 64; k++){
    float4 a4 = *(const float4*)&AsT[k][tr << 2];
    float4 b4 = *(const float4*)&Bs[k][tc << 2];
    float av[4] = {a4.x, a4.y, a4.z, a4.w};
    float bv[4] = {b4.x, b4.y, b4.z, b4.w};
    #pragma unroll
    for(int i = 0; i < 4; i++)
      #pragma unroll
      for(int j = 0; j < 4; j++) acc[i][j] += av[i] * bv[j];
  }
  float al4[4], ar4[4];
  #pragma unroll
  for(int j = 0; j < 4; j++){
    al4[j] = al2[(tc << 2) + j];
    ar4[j] = ar2[(tc << 2) + j];
  }
  int col = tc << 2;
  int half = col >> 6, c64 = col & 63;
  #pragma unroll
  for(int i = 0; i < 4; i++){
    int row = n0 + (tr << 2) + i;
    bool ok = row < NN;
    if(ok){
      union { __half2 h2[2]; float2 f2; } u;
      u.h2[0] = __floats2half2_rn(acc[i][0], acc[i][1]);
      u.h2[1] = __floats2half2_rn(acc[i][2], acc[i][3]);
      *(float2*)&ft2h[((size_t)half * NN + row) * 64 + c64] = u.f2;
    }
    float e1 = acc[i][0]*al4[0] + acc[i][1]*al4[1] + acc[i][2]*al4[2] + acc[i][3]*al4[3];
    float e2 = acc[i][0]*ar4[0] + acc[i][1]*ar4[1] + acc[i][2]*ar4[2] + acc[i][3]*ar4[3];
    #pragma unroll
    for(int off = 1; off < 32; off <<= 1){
      e1 += __shfl_xor(e1, off, 64);
      e2 += __shfl_xor(e2, off, 64);
    }
    if(tc == 0 && ok){ el[row] = e1; er[row] = e2; }
  }
}

// ---------------- layer-2 attn+agg, XCD-pinned per d-half, fma_mix gather ----------------
__global__ __launch_bounds__(256) void l2_head(
    const int* __restrict__ rowptr, const int* __restrict__ ssrc,
    const float* __restrict__ el, const float* __restrict__ er,
    const __half* __restrict__ ft2h, const float* __restrict__ b2,
    float* __restrict__ h2v){
  __shared__ int2 pairs[4][64];
  int b = blockIdx.x;
  int xcd = b & 7, s = b >> 3;
  int half = xcd >> 2;
  int chunk = (xcd & 3) * 1250 + s;
  int wave = threadIdx.x >> 6, lane = threadIdx.x & 63;
  int eg = lane >> 4, dg = lane & 15;
  int dn = chunk * 4 + wave;
  int base = rowptr[dn], deg = rowptr[dn + 1] - base;
  float4 acc = make_float4(0.f,0.f,0.f,0.f);
  float4 acc2 = make_float4(0.f,0.f,0.f,0.f);
  const char* fbase = (const char*)(ft2h + (size_t)half * NN * 64 + (dg << 2));
  int2* wp = pairs[wave];

  if(deg > 0 && deg <= 64){
    float er_d = er[dn];
    int off = 0; float p = 0.f;
    if(lane < deg){
      int sn = ssrc[base + lane];
      off = sn << 7;
      p = __expf(lrelu(el[sn] + er_d));
    }
    float inv = 1.f / wsum64(p);
    if(lane < deg) wp[lane] = make_int2(__float_as_int(p * inv), off);
    int i = eg;
    for(; i + 4 < deg; i += 8){
      int2 p1 = wp[i], p2 = wp[i + 4];
      float2 r1 = *(const float2*)(fbase + p1.y);
      float2 r2 = *(const float2*)(fbase + p2.y);
      float a1 = __int_as_float(p1.x), a2 = __int_as_float(p2.x);
      fma_mix_lo(acc.x, r1.x, a1);  fma_mix_hi(acc.y, r1.x, a1);
      fma_mix_lo(acc.z, r1.y, a1);  fma_mix_hi(acc.w, r1.y, a1);
      fma_mix_lo(acc2.x, r2.x, a2); fma_mix_hi(acc2.y, r2.x, a2);
      fma_mix_lo(acc2.z, r2.y, a2); fma_mix_hi(acc2.w, r2.y, a2);
    }
    if(i < deg){
      int2 p1 = wp[i];
      float2 r1 = *(const float2*)(fbase + p1.y);
      float a1 = __int_as_float(p1.x);
      fma_mix_lo(acc.x, r1.x, a1); fma_mix_hi(acc.y, r1.x, a1);
      fma_mix_lo(acc.z, r1.y, a1); fma_mix_hi(acc.w, r1.y, a1);
    }
  } else if(deg > 64){
    float er_d = er[dn];
    float sm = 0.f;
    for(int i = lane; i < deg; i += 64)
      sm += __expf(lrelu(el[ssrc[base + i]] + er_d));
    float inv = 1.f / wsum64(sm);
    for(int c = 0; c < deg; c += 64){
      int m = deg - c; if(m > 64) m = 64;
      if(lane < m){
        int sn = ssrc[base + c + lane];
        wp[lane] = make_int2(__float_as_int(__expf(lrelu(el[sn] + er_d)) * inv), sn << 7);
      }
      for(int i = eg; i < m; i += 4){
        int2 pr = wp[i];
        float a_i = __int_as_float(pr.x);
        float2 raw = *(const float2*)(fbase + pr.y);
        fma_mix_lo(acc.x, raw.x, a_i); fma_mix_hi(acc.y, raw.x, a_i);
        fma_mix_lo(acc.z, raw.y, a_i); fma_mix_hi(acc.w, raw.y, a_i);
      }
    }
  }
  acc.x += acc2.x; acc.y += acc2.y; acc.z += acc2.z; acc.w += acc2.w;
  #pragma unroll
  for(int off = 16; off <= 32; off <<= 1){
    acc.x += __shfl_xor(acc.x, off, 64);
    acc.y += __shfl_xor(acc.y, off, 64);
    acc.z += __shfl_xor(acc.z, off, 64);
    acc.w += __shfl_xor(acc.w, off, 64);
  }
  if(eg == 0){
    int doff = half * 64 + (dg << 2);
    const float* bp = &b2[doff];
    float4 o;
    o.x = fmaxf(acc.x + bp[0], 0.f);
    o.y = fmaxf(acc.y + bp[1], 0.f);
    o.z = fmaxf(acc.z + bp[2], 0.f);
    o.w = fmaxf(acc.w + bp[3], 0.f);
    *(float4*)&h2v[(size_t)dn * D2_ + doff] = o;
  }
}

// ---------------- per-graph max readout (graph_ids sorted) ----------------
__global__ __launch_bounds__(128) void graph_max(
    const float* __restrict__ h2v, const int* __restrict__ gid,
    int* __restrict__ rbuf){
  __shared__ int sb[2];
  int g = blockIdx.x, c = blockIdx.y, d = threadIdx.x;
  if(d < 2){
    int tgt = g + d;  // lower_bound(gid, tgt)
    int lo = 0, hi = NN;
    while(lo < hi){ int mid = (lo + hi) >> 1; if(gid[mid] < tgt) lo = mid + 1; else hi = mid; }
    sb[d] = lo;
  }
  __syncthreads();
  int gs = sb[0], ge = sb[1];
  int len = ge - gs;
  int cs = gs + (int)((long long)len * c / 4);
  int ce = gs + (int)((long long)len * (c + 1) / 4);
  float m0 = 0.f, m1 = 0.f, m2 = 0.f, m3 = 0.f;
  int n = cs;
  for(; n + 3 < ce; n += 4){
    m0 = fmaxf(m0, h2v[(size_t)(n + 0) * D2_ + d]);
    m1 = fmaxf(m1, h2v[(size_t)(n + 1) * D2_ + d]);
    m2 = fmaxf(m2, h2v[(size_t)(n + 2) * D2_ + d]);
    m3 = fmaxf(m3, h2v[(size_t)(n + 3) * D2_ + d]);
  }
  for(; n < ce; n++) m0 = fmaxf(m0, h2v[(size_t)n * D2_ + d]);
  float m = fmaxf(fmaxf(m0, m1), fmaxf(m2, m3));
  atomicMax(&rbuf[g * D2_ + d], __float_as_int(m));
}

__global__ void final_mlp(const float* __restrict__ r, const float* __restrict__ lw1,
                          const float* __restrict__ lb1, const float* __restrict__ lw2,
                          const float* __restrict__ lb2, float* __restrict__ out){
  __shared__ float rv[D2_];
  __shared__ float t[D2_];
  int g = blockIdx.x, j = threadIdx.x;
  rv[j] = r[g * D2_ + j];
  __syncthreads();
  float acc = lb1[j];
  #pragma unroll
  for(int k = 0; k < D2_; k++) acc += rv[k] * lw1[k * D2_ + j];
  acc = acc > 0.f ? acc : 0.f;
  t[j] = acc * lw2[j];
  __syncthreads();
  for(int off = 64; off > 0; off >>= 1){
    if(j < off) t[j] += t[j + off];
    __syncthreads();
  }
  if(j == 0){
    float v = t[0] + lb2[0];
    out[g] = v > 0.f ? v : 0.f;
  }
}

extern "C" void kernel_launch(void* const* d_in, const int* in_sizes, int n_in,
                              void* d_out, int out_size, void* d_ws, size_t ws_size,
                              hipStream_t stream) {
  const float* feat = (const float*)d_in[0];
  const int*   src  = (const int*)d_in[1];
  const int*   dst  = (const int*)d_in[2];
  const int*   gid  = (const int*)d_in[3];
  const float* W1   = (const float*)d_in[4];
  const float* al1  = (const float*)d_in[5];
  const float* ar1  = (const float*)d_in[6];
  const float* b1   = (const float*)d_in[7];
  const float* W2   = (const float*)d_in[8];
  const float* al2  = (const float*)d_in[9];
  const float* ar2  = (const float*)d_in[10];
  const float* b2   = (const float*)d_in[11];
  const float* lw1  = (const float*)d_in[12];
  const float* lb1  = (const float*)d_in[13];
  const float* lw2  = (const float*)d_in[14];
  const float* lb2  = (const float*)d_in[15];
  float* out = (float*)d_out;

  float* ws = (float*)d_ws;
  size_t o = 0;
  __half* ft1h = (__half*)(ws + o); o += (size_t)NN * F1 / 2;   // 25.6MB
  __half* out1h = (__half*)(ws + o); o += (size_t)NN * F1 / 2;  // 25.6MB
  __half* ft2h = (__half*)(ws + o); o += (size_t)NN * D2_ / 2;  // 5.12MB
  float* h2v  = ws + o; o += (size_t)NN * D2_;                  // 10.24MB
  float* el1  = ws + o; o += (size_t)NN * H1_;
  float* er1  = ws + o; o += (size_t)NN * H1_;
  float* el2  = ws + o; o += NN;
  float* er2  = ws + o; o += NN;
  float* rbuf = ws + o; o += (size_t)GG * D2_;
  int* hist   = (int*)(ws + o); o += NN;
  int* rowptr = (int*)(ws + o); o += NN + 1;
  int* cursor = (int*)(ws + o); o += NN;
  int* bsum   = (int*)(ws + o); o += 128;
  int* ssrc   = (int*)(ws + o); o += EE;

  // ---- CSR build ----
  hipMemsetAsync(hist, 0, (size_t)NN * 4, stream);
  hist_k<<<cdiv(EE,256),256,0,stream>>>(dst, hist);
  scan1<<<cdiv(NN,256),256,0,stream>>>(hist, rowptr, bsum);
  scan2<<<cdiv(NN,256),256,0,stream>>>(rowptr, bsum, cursor);
  scatter_k<<<cdiv(EE,256),256,0,stream>>>(src, dst, cursor, ssrc);

  // ---- layer 1 ----
  gemm1<<<dim3(H1_, cdiv(NN,64)), 256, 0, stream>>>(feat, W1, al1, ar1, ft1h, el1, er1);
  l1_head<<<50000, 256, 0, stream>>>(rowptr, ssrc, el1, er1, ft1h, b1, out1h);

  // ---- layer 2 (head-sum fused into gemm2 A-load) ----
  gemm2<<<cdiv(NN,32), 256, 0, stream>>>(out1h, W2, al2, ar2, ft2h, el2, er2);
  l2_head<<<10000, 256, 0, stream>>>(rowptr, ssrc, el2, er2, ft2h, b2, h2v);

  // ---- readout + MLP ----
  hipMemsetAsync(rbuf, 0, (size_t)GG * D2_ * 4, stream);
  graph_max<<<dim3(GG, 4), 128, 0, stream>>>(h2v, gid, (int*)rbuf);
  final_mlp<<<GG, D2_, 0, stream>>>(rbuf, lw1, lb1, lw2, lb2, out);
}

// Round 11
// 181.311 us; speedup vs baseline: 2.5917x; 1.1374x over previous
//
#include <hip/hip_runtime.h>
#include <hip/hip_fp16.h>

#define NN 20000
#define EE 320000
#define GG 50
#define IN_ 64
#define H1_ 10
#define D1_ 64
#define D2_ 128
#define F1 640   /* H1_*D1_ */
#define NEG 0.2f

static inline int cdiv(long long a, int b){ return (int)((a + b - 1) / b); }

__device__ inline float lrelu(float x){ return x > 0.f ? x : NEG * x; }

// acc += (f16 lo/hi of packed) * a   — fp32 accumulate, single VOP3P op
__device__ inline void fma_mix_lo(float& acc, float packed, float a){
  asm("v_fma_mix_f32 %0, %1, %2, %0 op_sel_hi:[1,0,0]"
      : "+v"(acc) : "v"(packed), "v"(a));
}
__device__ inline void fma_mix_hi(float& acc, float packed, float a){
  asm("v_fma_mix_f32 %0, %1, %2, %0 op_sel:[1,0,0] op_sel_hi:[1,0,0]"
      : "+v"(acc) : "v"(packed), "v"(a));
}

// ---------------- CSR build ----------------
__global__ void hist_k(const int* __restrict__ dst, int* __restrict__ hist){
  int e = blockIdx.x * blockDim.x + threadIdx.x;
  if(e < EE) atomicAdd(&hist[dst[e]], 1);
}

__global__ __launch_bounds__(256) void scan1(
    const int* __restrict__ hist, int* __restrict__ rowptr, int* __restrict__ bsum){
  __shared__ int tmp[256];
  int b = blockIdx.x, t = threadIdx.x;
  int idx = b * 256 + t;
  int v = idx < NN ? hist[idx] : 0;
  tmp[t] = v;
  __syncthreads();
  for(int off = 1; off < 256; off <<= 1){
    int x = t >= off ? tmp[t - off] : 0;
    __syncthreads();
    tmp[t] += x;
    __syncthreads();
  }
  if(idx < NN) rowptr[idx] = tmp[t] - v;
  if(t == 255) bsum[b] = tmp[255];
}

__global__ __launch_bounds__(256) void scan2(
    int* __restrict__ rowptr, const int* __restrict__ bsum, int* __restrict__ cursor){
  __shared__ int pre;
  int b = blockIdx.x, t = threadIdx.x;
  if(t == 0){
    int s = 0;
    for(int i = 0; i < b; i++) s += bsum[i];
    pre = s;
  }
  __syncthreads();
  int idx = b * 256 + t;
  if(idx < NN){
    int r = rowptr[idx] + pre;
    rowptr[idx] = r;
    cursor[idx] = r;
  }
  if(idx == 0) rowptr[NN] = EE;
}

__global__ void scatter_k(const int* __restrict__ src, const int* __restrict__ dst,
                          int* __restrict__ cursor, int* __restrict__ ssrc){
  int e = blockIdx.x * blockDim.x + threadIdx.x;
  if(e >= EE) return;
  int pos = atomicAdd(&cursor[dst[e]], 1);
  ssrc[pos] = src[e];
}

// ---------------- GEMM1: ft1h[h][n][64] fp16; elT/erT[h][n] ----------------
__global__ __launch_bounds__(256) void gemm1(
    const float* __restrict__ feat, const float* __restrict__ W1,
    const float* __restrict__ al1, const float* __restrict__ ar1,
    __half* __restrict__ ft1h, float* __restrict__ elT, float* __restrict__ erT){
  __shared__ float AsT[64][68];  // [k][r]
  __shared__ float Bs[64][68];   // [k][c]
  int h = blockIdx.x;
  int n0 = blockIdx.y * 64;
  int tid = threadIdx.x;
  #pragma unroll
  for(int l = 0; l < 4; l++){
    int idx = tid + l * 256;
    int r = idx >> 4, c4 = (idx & 15) << 2;
    float4 v = make_float4(0.f,0.f,0.f,0.f);
    if(n0 + r < NN) v = *(const float4*)&feat[(size_t)(n0 + r) * IN_ + c4];
    AsT[c4+0][r] = v.x; AsT[c4+1][r] = v.y; AsT[c4+2][r] = v.z; AsT[c4+3][r] = v.w;
    float4 w = *(const float4*)&W1[(size_t)(idx >> 4) * F1 + h * 64 + c4];
    *(float4*)&Bs[idx >> 4][c4] = w;
  }
  __syncthreads();
  int tr = tid >> 4, tc = tid & 15;
  float acc[4][4];
  #pragma unroll
  for(int i = 0; i < 4; i++)
    #pragma unroll
    for(int j = 0; j < 4; j++) acc[i][j] = 0.f;
  #pragma unroll 8
  for(int k = 0; k < 64; k++){
    float4 a4 = *(const float4*)&AsT[k][tr << 2];
    float4 b4 = *(const float4*)&Bs[k][tc << 2];
    float av[4] = {a4.x, a4.y, a4.z, a4.w};
    float bv[4] = {b4.x, b4.y, b4.z, b4.w};
    #pragma unroll
    for(int i = 0; i < 4; i++)
      #pragma unroll
      for(int j = 0; j < 4; j++) acc[i][j] += av[i] * bv[j];
  }
  float al4[4], ar4[4];
  #pragma unroll
  for(int j = 0; j < 4; j++){
    al4[j] = al1[h * 64 + (tc << 2) + j];
    ar4[j] = ar1[h * 64 + (tc << 2) + j];
  }
  #pragma unroll
  for(int i = 0; i < 4; i++){
    int row = n0 + (tr << 2) + i;
    bool ok = row < NN;
    if(ok){
      union { __half2 h2[2]; float2 f2; } u;
      u.h2[0] = __floats2half2_rn(acc[i][0], acc[i][1]);
      u.h2[1] = __floats2half2_rn(acc[i][2], acc[i][3]);
      *(float2*)&ft1h[((size_t)h * NN + row) * 64 + (tc << 2)] = u.f2;
    }
    float e1 = acc[i][0]*al4[0] + acc[i][1]*al4[1] + acc[i][2]*al4[2] + acc[i][3]*al4[3];
    float e2 = acc[i][0]*ar4[0] + acc[i][1]*ar4[1] + acc[i][2]*ar4[2] + acc[i][3]*ar4[3];
    #pragma unroll
    for(int off = 1; off < 16; off <<= 1){
      e1 += __shfl_xor(e1, off, 64);
      e2 += __shfl_xor(e2, off, 64);
    }
    if(tc == 0 && ok){
      elT[(size_t)h * NN + row] = e1;
      erT[(size_t)h * NN + row] = e2;
    }
  }
}

// ---------------- layer-1 attn+agg: 2 (dn,h) pairs per wave, 32 lanes each ----------------
// blockIdx%8 = XCD; phase A (slot<2500): h=xcd, 8 dn/block; phase B: h=8+(xcd>>2).
// Per 32-lane half: softmax edge=lane (deg<=32 ~99.99%), agg 2 eg x 16 dg x 4 dims.
__global__ __launch_bounds__(256) void l1_head(
    const int* __restrict__ rowptr, const int* __restrict__ ssrc,
    const float* __restrict__ elT, const float* __restrict__ erT,
    const __half* __restrict__ ft1h, const float* __restrict__ b1,
    __half* __restrict__ out1h){
  __shared__ int2 pairs[4][2][32];
  int b = blockIdx.x;
  int xcd = b & 7, slot = b >> 3;
  int h, blk;
  if(slot < 2500){ h = xcd; blk = slot; }
  else { int s = slot - 2500; h = 8 + (xcd >> 2); blk = (xcd & 3) * 625 + s; }
  int wave = threadIdx.x >> 6, lane = threadIdx.x & 63;
  int half = lane >> 5, l32 = lane & 31;
  int eg = l32 >> 4, dg = l32 & 15;
  int dn = blk * 8 + wave * 2 + half;
  int base = rowptr[dn], deg = rowptr[dn + 1] - base;
  float4 acc = make_float4(0.f,0.f,0.f,0.f);
  const char* fbase = (const char*)(ft1h + (size_t)h * NN * 64) + (dg << 3);
  const float* elh = elT + (size_t)h * NN;
  float er_h = erT[(size_t)h * NN + dn];
  int2* wp = pairs[wave][half];

  if(__any(deg > 32)){
    // chunked fallback (rare): recompute exp per chunk
    float sm = 0.f;
    for(int i = l32; i < deg; i += 32)
      sm += __expf(lrelu(elh[ssrc[base + i]] + er_h));
    #pragma unroll
    for(int o = 1; o < 32; o <<= 1) sm += __shfl_xor(sm, o, 64);
    float inv = deg > 0 ? 1.f / sm : 0.f;
    for(int c = 0; c < deg; c += 32){
      int m = deg - c; if(m > 32) m = 32;
      if(l32 < m){
        int sn = ssrc[base + c + l32];
        wp[l32] = make_int2(__float_as_int(__expf(lrelu(elh[sn] + er_h)) * inv), sn << 7);
      }
      for(int i = eg; i < m; i += 2){
        int2 pr = wp[i];
        float a_i = __int_as_float(pr.x);
        float2 raw = *(const float2*)(fbase + pr.y);
        fma_mix_lo(acc.x, raw.x, a_i); fma_mix_hi(acc.y, raw.x, a_i);
        fma_mix_lo(acc.z, raw.y, a_i); fma_mix_hi(acc.w, raw.y, a_i);
      }
    }
  } else {
    float p = 0.f; int off = 0;
    if(l32 < deg){
      int sn = ssrc[base + l32];
      off = sn << 7;  // byte offset of row
      p = __expf(lrelu(elh[sn] + er_h));
    }
    float sm = p;
    #pragma unroll
    for(int o = 1; o < 32; o <<= 1) sm += __shfl_xor(sm, o, 64);
    float inv = deg > 0 ? 1.f / sm : 0.f;
    if(l32 < deg) wp[l32] = make_int2(__float_as_int(p * inv), off);
    int i = eg;
    for(; i + 2 < deg; i += 4){
      int2 p1 = wp[i], p2 = wp[i + 2];
      float2 r1 = *(const float2*)(fbase + p1.y);
      float2 r2 = *(const float2*)(fbase + p2.y);
      float a1 = __int_as_float(p1.x), a2 = __int_as_float(p2.x);
      fma_mix_lo(acc.x, r1.x, a1); fma_mix_hi(acc.y, r1.x, a1);
      fma_mix_lo(acc.z, r1.y, a1); fma_mix_hi(acc.w, r1.y, a1);
      fma_mix_lo(acc.x, r2.x, a2); fma_mix_hi(acc.y, r2.x, a2);
      fma_mix_lo(acc.z, r2.y, a2); fma_mix_hi(acc.w, r2.y, a2);
    }
    if(i < deg){
      int2 p1 = wp[i];
      float2 r1 = *(const float2*)(fbase + p1.y);
      float a1 = __int_as_float(p1.x);
      fma_mix_lo(acc.x, r1.x, a1); fma_mix_hi(acc.y, r1.x, a1);
      fma_mix_lo(acc.z, r1.y, a1); fma_mix_hi(acc.w, r1.y, a1);
    }
  }
  // cross edge-group reduce (within 32-lane half)
  acc.x += __shfl_xor(acc.x, 16, 64);
  acc.y += __shfl_xor(acc.y, 16, 64);
  acc.z += __shfl_xor(acc.z, 16, 64);
  acc.w += __shfl_xor(acc.w, 16, 64);
  if(eg == 0){
    int d = dg << 2;
    const float* bp = &b1[h * 64 + d];
    union { __half2 h2[2]; float2 f2; } u;
    u.h2[0] = __floats2half2_rn(fmaxf(acc.x + bp[0], 0.f), fmaxf(acc.y + bp[1], 0.f));
    u.h2[1] = __floats2half2_rn(fmaxf(acc.z + bp[2], 0.f), fmaxf(acc.w + bp[3], 0.f));
    *(float2*)&out1h[(size_t)dn * F1 + h * 64 + d] = u.f2;
  }
}

// ---------------- GEMM2: A = head-sum(out1h fp16) on the fly; fp16 out + el2/er2 ----------------
__global__ __launch_bounds__(256) void gemm2(
    const __half* __restrict__ out1h, const float* __restrict__ W2,
    const float* __restrict__ al2, const float* __restrict__ ar2,
    __half* __restrict__ ft2h, float* __restrict__ el, float* __restrict__ er){
  __shared__ float AsT[64][36];   // [k][r], r<32
  __shared__ float Bs[64][132];   // [k][c]
  int n0 = blockIdx.x * 32;
  int tid = threadIdx.x;
  #pragma unroll
  for(int l = 0; l < 2; l++){
    int idx = tid + l * 256;
    int r = idx >> 4, c4 = (idx & 15) << 2;
    float4 sv = make_float4(0.f,0.f,0.f,0.f);
    if(n0 + r < NN){
      const __half* rp = &out1h[(size_t)(n0 + r) * F1 + c4];
      #pragma unroll
      for(int hh = 0; hh < H1_; hh++){
        float2 raw = *(const float2*)(rp + hh * 64);
        const __half2* hp = (const __half2*)&raw;
        float2 f0 = __half22float2(hp[0]);
        float2 f1 = __half22float2(hp[1]);
        sv.x += f0.x; sv.y += f0.y; sv.z += f1.x; sv.w += f1.y;
      }
    }
    AsT[c4+0][r] = sv.x; AsT[c4+1][r] = sv.y; AsT[c4+2][r] = sv.z; AsT[c4+3][r] = sv.w;
  }
  #pragma unroll
  for(int l = 0; l < 8; l++){
    int idx = tid + l * 256;
    int k = idx >> 5, c4 = (idx & 31) << 2;
    *(float4*)&Bs[k][c4] = *(const float4*)&W2[(size_t)k * D2_ + c4];
  }
  __syncthreads();
  int tr = tid >> 5, tc = tid & 31;
  float acc[4][4];
  #pragma unroll
  for(int i = 0; i < 4; i++)
    #pragma unroll
    for(int j = 0; j < 4; j++) acc[i][j] = 0.f;
  #pragma unroll 8
  for(int k = 0; k < 64; k++){
    float4 a4 = *(const float4*)&AsT[k][tr << 2];
    float4 b4 = *(const float4*)&Bs[k][tc << 2];
    float av[4] = {a4.x, a4.y, a4.z, a4.w};
    float bv[4] = {b4.x, b4.y, b4.z, b4.w};
    #pragma unroll
    for(int i = 0; i < 4; i++)
      #pragma unroll
      for(int j = 0; j < 4; j++) acc[i][j] += av[i] * bv[j];
  }
  float al4[4], ar4[4];
  #pragma unroll
  for(int j = 0; j < 4; j++){
    al4[j] = al2[(tc << 2) + j];
    ar4[j] = ar2[(tc << 2) + j];
  }
  int col = tc << 2;
  int half = col >> 6, c64 = col & 63;
  #pragma unroll
  for(int i = 0; i < 4; i++){
    int row = n0 + (tr << 2) + i;
    bool ok = row < NN;
    if(ok){
      union { __half2 h2[2]; float2 f2; } u;
      u.h2[0] = __floats2half2_rn(acc[i][0], acc[i][1]);
      u.h2[1] = __floats2half2_rn(acc[i][2], acc[i][3]);
      *(float2*)&ft2h[((size_t)half * NN + row) * 64 + c64] = u.f2;
    }
    float e1 = acc[i][0]*al4[0] + acc[i][1]*al4[1] + acc[i][2]*al4[2] + acc[i][3]*al4[3];
    float e2 = acc[i][0]*ar4[0] + acc[i][1]*ar4[1] + acc[i][2]*ar4[2] + acc[i][3]*ar4[3];
    #pragma unroll
    for(int off = 1; off < 32; off <<= 1){
      e1 += __shfl_xor(e1, off, 64);
      e2 += __shfl_xor(e2, off, 64);
    }
    if(tc == 0 && ok){ el[row] = e1; er[row] = e2; }
  }
}

// ---------------- layer-2 attn+agg: 2 dn per wave (same d-half), 32 lanes each ----------------
__global__ __launch_bounds__(256) void l2_head(
    const int* __restrict__ rowptr, const int* __restrict__ ssrc,
    const float* __restrict__ el, const float* __restrict__ er,
    const __half* __restrict__ ft2h, const float* __restrict__ b2,
    float* __restrict__ h2v){
  __shared__ int2 pairs[4][2][32];
  int b = blockIdx.x;
  int xcd = b & 7, slot = b >> 3;
  int halfd = xcd >> 2;
  int blk = (xcd & 3) * 625 + slot;
  int wave = threadIdx.x >> 6, lane = threadIdx.x & 63;
  int half = lane >> 5, l32 = lane & 31;
  int eg = l32 >> 4, dg = l32 & 15;
  int dn = blk * 8 + wave * 2 + half;
  int base = rowptr[dn], deg = rowptr[dn + 1] - base;
  float4 acc = make_float4(0.f,0.f,0.f,0.f);
  const char* fbase = (const char*)(ft2h + (size_t)halfd * NN * 64) + (dg << 3);
  float er_d = er[dn];
  int2* wp = pairs[wave][half];

  if(__any(deg > 32)){
    float sm = 0.f;
    for(int i = l32; i < deg; i += 32)
      sm += __expf(lrelu(el[ssrc[base + i]] + er_d));
    #pragma unroll
    for(int o = 1; o < 32; o <<= 1) sm += __shfl_xor(sm, o, 64);
    float inv = deg > 0 ? 1.f / sm : 0.f;
    for(int c = 0; c < deg; c += 32){
      int m = deg - c; if(m > 32) m = 32;
      if(l32 < m){
        int sn = ssrc[base + c + l32];
        wp[l32] = make_int2(__float_as_int(__expf(lrelu(el[sn] + er_d)) * inv), sn << 7);
      }
      for(int i = eg; i < m; i += 2){
        int2 pr = wp[i];
        float a_i = __int_as_float(pr.x);
        float2 raw = *(const float2*)(fbase + pr.y);
        fma_mix_lo(acc.x, raw.x, a_i); fma_mix_hi(acc.y, raw.x, a_i);
        fma_mix_lo(acc.z, raw.y, a_i); fma_mix_hi(acc.w, raw.y, a_i);
      }
    }
  } else {
    float p = 0.f; int off = 0;
    if(l32 < deg){
      int sn = ssrc[base + l32];
      off = sn << 7;
      p = __expf(lrelu(el[sn] + er_d));
    }
    float sm = p;
    #pragma unroll
    for(int o = 1; o < 32; o <<= 1) sm += __shfl_xor(sm, o, 64);
    float inv = deg > 0 ? 1.f / sm : 0.f;
    if(l32 < deg) wp[l32] = make_int2(__float_as_int(p * inv), off);
    int i = eg;
    for(; i + 2 < deg; i += 4){
      int2 p1 = wp[i], p2 = wp[i + 2];
      float2 r1 = *(const float2*)(fbase + p1.y);
      float2 r2 = *(const float2*)(fbase + p2.y);
      float a1 = __int_as_float(p1.x), a2 = __int_as_float(p2.x);
      fma_mix_lo(acc.x, r1.x, a1); fma_mix_hi(acc.y, r1.x, a1);
      fma_mix_lo(acc.z, r1.y, a1); fma_mix_hi(acc.w, r1.y, a1);
      fma_mix_lo(acc.x, r2.x, a2); fma_mix_hi(acc.y, r2.x, a2);
      fma_mix_lo(acc.z, r2.y, a2); fma_mix_hi(acc.w, r2.y, a2);
    }
    if(i < deg){
      int2 p1 = wp[i];
      float2 r1 = *(const float2*)(fbase + p1.y);
      float a1 = __int_as_float(p1.x);
      fma_mix_lo(acc.x, r1.x, a1); fma_mix_hi(acc.y, r1.x, a1);
      fma_mix_lo(acc.z, r1.y, a1); fma_mix_hi(acc.w, r1.y, a1);
    }
  }
  acc.x += __shfl_xor(acc.x, 16, 64);
  acc.y += __shfl_xor(acc.y, 16, 64);
  acc.z += __shfl_xor(acc.z, 16, 64);
  acc.w += __shfl_xor(acc.w, 16, 64);
  if(eg == 0){
    int doff = halfd * 64 + (dg << 2);
    const float* bp = &b2[doff];
    float4 o;
    o.x = fmaxf(acc.x + bp[0], 0.f);
    o.y = fmaxf(acc.y + bp[1], 0.f);
    o.z = fmaxf(acc.z + bp[2], 0.f);
    o.w = fmaxf(acc.w + bp[3], 0.f);
    *(float4*)&h2v[(size_t)dn * D2_ + doff] = o;
  }
}

// ---------------- per-graph max readout (graph_ids sorted) ----------------
__global__ __launch_bounds__(128) void graph_max(
    const float* __restrict__ h2v, const int* __restrict__ gid,
    int* __restrict__ rbuf){
  __shared__ int sb[2];
  int g = blockIdx.x, c = blockIdx.y, d = threadIdx.x;
  if(d < 2){
    int tgt = g + d;  // lower_bound(gid, tgt)
    int lo = 0, hi = NN;
    while(lo < hi){ int mid = (lo + hi) >> 1; if(gid[mid] < tgt) lo = mid + 1; else hi = mid; }
    sb[d] = lo;
  }
  __syncthreads();
  int gs = sb[0], ge = sb[1];
  int len = ge - gs;
  int cs = gs + (int)((long long)len * c / 4);
  int ce = gs + (int)((long long)len * (c + 1) / 4);
  float m0 = 0.f, m1 = 0.f, m2 = 0.f, m3 = 0.f;
  int n = cs;
  for(; n + 3 < ce; n += 4){
    m0 = fmaxf(m0, h2v[(size_t)(n + 0) * D2_ + d]);
    m1 = fmaxf(m1, h2v[(size_t)(n + 1) * D2_ + d]);
    m2 = fmaxf(m2, h2v[(size_t)(n + 2) * D2_ + d]);
    m3 = fmaxf(m3, h2v[(size_t)(n + 3) * D2_ + d]);
  }
  for(; n < ce; n++) m0 = fmaxf(m0, h2v[(size_t)n * D2_ + d]);
  float m = fmaxf(fmaxf(m0, m1), fmaxf(m2, m3));
  atomicMax(&rbuf[g * D2_ + d], __float_as_int(m));
}

__global__ void final_mlp(const float* __restrict__ r, const float* __restrict__ lw1,
                          const float* __restrict__ lb1, const float* __restrict__ lw2,
                          const float* __restrict__ lb2, float* __restrict__ out){
  __shared__ float rv[D2_];
  __shared__ float t[D2_];
  int g = blockIdx.x, j = threadIdx.x;
  rv[j] = r[g * D2_ + j];
  __syncthreads();
  float acc = lb1[j];
  #pragma unroll
  for(int k = 0; k < D2_; k++) acc += rv[k] * lw1[k * D2_ + j];
  acc = acc > 0.f ? acc : 0.f;
  t[j] = acc * lw2[j];
  __syncthreads();
  for(int off = 64; off > 0; off >>= 1){
    if(j < off) t[j] += t[j + off];
    __syncthreads();
  }
  if(j == 0){
    float v = t[0] + lb2[0];
    out[g] = v > 0.f ? v : 0.f;
  }
}

extern "C" void kernel_launch(void* const* d_in, const int* in_sizes, int n_in,
                              void* d_out, int out_size, void* d_ws, size_t ws_size,
                              hipStream_t stream) {
  const float* feat = (const float*)d_in[0];
  const int*   src  = (const int*)d_in[1];
  const int*   dst  = (const int*)d_in[2];
  const int*   gid  = (const int*)d_in[3];
  const float* W1   = (const float*)d_in[4];
  const float* al1  = (const float*)d_in[5];
  const float* ar1  = (const float*)d_in[6];
  const float* b1   = (const float*)d_in[7];
  const float* W2   = (const float*)d_in[8];
  const float* al2  = (const float*)d_in[9];
  const float* ar2  = (const float*)d_in[10];
  const float* b2   = (const float*)d_in[11];
  const float* lw1  = (const float*)d_in[12];
  const float* lb1  = (const float*)d_in[13];
  const float* lw2  = (const float*)d_in[14];
  const float* lb2  = (const float*)d_in[15];
  float* out = (float*)d_out;

  float* ws = (float*)d_ws;
  size_t o = 0;
  __half* ft1h = (__half*)(ws + o); o += (size_t)NN * F1 / 2;   // 25.6MB
  __half* out1h = (__half*)(ws + o); o += (size_t)NN * F1 / 2;  // 25.6MB
  __half* ft2h = (__half*)(ws + o); o += (size_t)NN * D2_ / 2;  // 5.12MB
  float* h2v  = ws + o; o += (size_t)NN * D2_;                  // 10.24MB
  float* el1  = ws + o; o += (size_t)NN * H1_;
  float* er1  = ws + o; o += (size_t)NN * H1_;
  float* el2  = ws + o; o += NN;
  float* er2  = ws + o; o += NN;
  float* rbuf = ws + o; o += (size_t)GG * D2_;
  int* hist   = (int*)(ws + o); o += NN;
  int* rowptr = (int*)(ws + o); o += NN + 1;
  int* cursor = (int*)(ws + o); o += NN;
  int* bsum   = (int*)(ws + o); o += 128;
  int* ssrc   = (int*)(ws + o); o += EE;

  // ---- CSR build ----
  hipMemsetAsync(hist, 0, (size_t)NN * 4, stream);
  hist_k<<<cdiv(EE,256),256,0,stream>>>(dst, hist);
  scan1<<<cdiv(NN,256),256,0,stream>>>(hist, rowptr, bsum);
  scan2<<<cdiv(NN,256),256,0,stream>>>(rowptr, bsum, cursor);
  scatter_k<<<cdiv(EE,256),256,0,stream>>>(src, dst, cursor, ssrc);

  // ---- layer 1 ----
  gemm1<<<dim3(H1_, cdiv(NN,64)), 256, 0, stream>>>(feat, W1, al1, ar1, ft1h, el1, er1);
  l1_head<<<25000, 256, 0, stream>>>(rowptr, ssrc, el1, er1, ft1h, b1, out1h);

  // ---- layer 2 (head-sum fused into gemm2 A-load) ----
  gemm2<<<cdiv(NN,32), 256, 0, stream>>>(out1h, W2, al2, ar2, ft2h, el2, er2);
  l2_head<<<5000, 256, 0, stream>>>(rowptr, ssrc, el2, er2, ft2h, b2, h2v);

  // ---- readout + MLP ----
  hipMemsetAsync(rbuf, 0, (size_t)GG * D2_ * 4, stream);
  graph_max<<<dim3(GG, 4), 128, 0, stream>>>(h2v, gid, (int*)rbuf);
  final_mlp<<<GG, D2_, 0, stream>>>(rbuf, lw1, lb1, lw2, lb2, out);
}